// Round 1
// baseline (954.327 us; speedup 1.0000x reference)
//
#include <hip/hip_runtime.h>
#include <hip/hip_bf16.h>

#define NN 100000
#define NE 3200000
#define INC 256
#define HID 64
#define OUTC 2
#define EPSV 1e-5f

#define SCAN_CHUNK 1024
#define NBLK ((NN + SCAN_CHUNK - 1) / SCAN_CHUNK)   // 98

// ---------------- histogram: in-degree counts ----------------
__global__ void hist_kernel(const int* __restrict__ dst, int* __restrict__ cnt) {
    int i = blockIdx.x * blockDim.x + threadIdx.x;
    int stride = gridDim.x * blockDim.x;
    for (; i < NE; i += stride) atomicAdd(&cnt[dst[i]], 1);
}

// ---------------- scan step 1: per-chunk totals ----------------
__global__ void scan_btot_kernel(const int* __restrict__ cnt, int* __restrict__ btot) {
    __shared__ int red[4];
    int b = blockIdx.x, t = threadIdx.x;
    int base = b * SCAN_CHUNK;
    int v = 0;
    for (int j = t; j < SCAN_CHUNK; j += 256) {
        int idx = base + j;
        v += (idx < NN) ? cnt[idx] : 0;
    }
    for (int o = 32; o; o >>= 1) v += __shfl_xor(v, o);
    int wave = t >> 6, lane = t & 63;
    if (lane == 0) red[wave] = v;
    __syncthreads();
    if (t == 0) btot[b] = red[0] + red[1] + red[2] + red[3];
}

// ---------------- scan step 2: exclusive scan of chunk totals ----------------
__global__ void scan_boff_kernel(const int* __restrict__ btot, int* __restrict__ boff) {
    __shared__ int wtot[2];
    int t = threadIdx.x;           // 128 threads
    int lane = t & 63, wave = t >> 6;
    int v = (t < NBLK) ? btot[t] : 0;
    int s = v;
    for (int o = 1; o < 64; o <<= 1) {
        int u = __shfl_up(s, o);
        if (lane >= o) s += u;
    }
    if (lane == 63) wtot[wave] = s;
    __syncthreads();
    int add = (wave == 1) ? wtot[0] : 0;
    if (t < NBLK) boff[t] = s - v + add;   // exclusive prefix
}

// ---------------- scan step 3: full rowptr ----------------
__global__ void scan_rowptr_kernel(const int* __restrict__ cnt, const int* __restrict__ boff,
                                   int* __restrict__ rowptr) {
    __shared__ int wsum[4];
    int b = blockIdx.x, t = threadIdx.x;
    int lane = t & 63, wave = t >> 6;
    int idx = b * SCAN_CHUNK + t * 4;
    int c0 = (idx + 0 < NN) ? cnt[idx + 0] : 0;
    int c1 = (idx + 1 < NN) ? cnt[idx + 1] : 0;
    int c2 = (idx + 2 < NN) ? cnt[idx + 2] : 0;
    int c3 = (idx + 3 < NN) ? cnt[idx + 3] : 0;
    int local = c0 + c1 + c2 + c3;
    int s = local;
    for (int o = 1; o < 64; o <<= 1) {
        int u = __shfl_up(s, o);
        if (lane >= o) s += u;
    }
    if (lane == 63) wsum[wave] = s;
    __syncthreads();
    if (t == 0) {
        int run = 0;
        for (int w = 0; w < 4; w++) { int x = wsum[w]; wsum[w] = run; run += x; }
    }
    __syncthreads();
    int start = boff[b] + wsum[wave] + (s - local);
    if (idx + 0 < NN) rowptr[idx + 0] = start;
    if (idx + 1 < NN) rowptr[idx + 1] = start + c0;
    if (idx + 2 < NN) rowptr[idx + 2] = start + c0 + c1;
    if (idx + 3 < NN) rowptr[idx + 3] = start + c0 + c1 + c2;
    if (b == 0 && t == 0) rowptr[NN] = NE;
}

// ---------------- scatter edges into CSR, precompute norm ----------------
__global__ void scatter_kernel(const int* __restrict__ src, const int* __restrict__ dst,
                               const int* __restrict__ cnt, const int* __restrict__ rowptr,
                               int* __restrict__ fill, int* __restrict__ e_src,
                               float* __restrict__ e_norm) {
    int i = blockIdx.x * blockDim.x + threadIdx.x;
    int stride = gridDim.x * blockDim.x;
    for (; i < NE; i += stride) {
        int s = src[i], d = dst[i];
        int pos = rowptr[d] + atomicAdd(&fill[d], 1);
        e_src[pos] = s;
        e_norm[pos] = rsqrtf((float)(cnt[s] + 1) * (float)(cnt[d] + 1));
    }
}

// ---------------- GEMM1: XW1 = x @ W1  ([N,256]@[256,64]) ----------------
// block = 256 threads = 4 waves; each wave computes 4 rows; lane = output channel.
// W1 staged in LDS [k][c]; x rows read via wave-uniform (scalar) float4 loads.
__global__ __launch_bounds__(256) void gemm1_kernel(const float* __restrict__ x,
                                                    const float* __restrict__ W1,
                                                    float* __restrict__ xw1) {
    __shared__ float wlds[INC * HID];   // 64 KB
    for (int i = threadIdx.x; i < (INC * HID) / 4; i += 256)
        ((float4*)wlds)[i] = ((const float4*)W1)[i];
    __syncthreads();
    int lane = threadIdx.x & 63;
    int wave = threadIdx.x >> 6;
    int r0 = __builtin_amdgcn_readfirstlane(blockIdx.x * 16 + wave * 4);
    const float4* x0 = (const float4*)(x + (size_t)(r0 + 0) * INC);
    const float4* x1 = (const float4*)(x + (size_t)(r0 + 1) * INC);
    const float4* x2 = (const float4*)(x + (size_t)(r0 + 2) * INC);
    const float4* x3 = (const float4*)(x + (size_t)(r0 + 3) * INC);
    float a0 = 0.f, a1 = 0.f, a2 = 0.f, a3 = 0.f;
#pragma unroll 8
    for (int k4 = 0; k4 < INC / 4; k4++) {
        float4 v0 = x0[k4], v1 = x1[k4], v2 = x2[k4], v3 = x3[k4];
        const float* wk = wlds + k4 * 4 * HID + lane;
        float w0 = wk[0], w1 = wk[64], w2 = wk[128], w3 = wk[192];
        a0 += v0.x * w0 + v0.y * w1 + v0.z * w2 + v0.w * w3;
        a1 += v1.x * w0 + v1.y * w1 + v1.z * w2 + v1.w * w3;
        a2 += v2.x * w0 + v2.y * w1 + v2.z * w2 + v2.w * w3;
        a3 += v3.x * w0 + v3.y * w1 + v3.z * w2 + v3.w * w3;
    }
    xw1[(size_t)(r0 + 0) * HID + lane] = a0;
    xw1[(size_t)(r0 + 1) * HID + lane] = a1;
    xw1[(size_t)(r0 + 2) * HID + lane] = a2;
    xw1[(size_t)(r0 + 3) * HID + lane] = a3;
}

// ---------------- agg1: h1 = A_hat @ XW1 + b1, fused BN1 stats ----------------
// wave per dst node, lane = channel; coalesced 256B gathers of XW1[src].
__global__ __launch_bounds__(256) void agg1_kernel(const float* __restrict__ xw1,
                                                   const int* __restrict__ rowptr,
                                                   const int* __restrict__ e_src,
                                                   const float* __restrict__ e_norm,
                                                   const int* __restrict__ cnt,
                                                   const float* __restrict__ b1,
                                                   float* __restrict__ h1,
                                                   float* __restrict__ sums1) {
    __shared__ float lsum[4][64], lsq[4][64];
    int lane = threadIdx.x & 63;
    int wave = threadIdx.x >> 6;
    int wid = blockIdx.x * 4 + wave;
    int wstride = gridDim.x * 4;
    float bs = b1[lane];
    float ssum = 0.f, ssq = 0.f;
    for (int d0 = wid; d0 < NN; d0 += wstride) {
        int d = __builtin_amdgcn_readfirstlane(d0);
        int beg = rowptr[d], end = rowptr[d + 1];
        float acc = 0.f;
        int e = beg;
        for (; e + 1 < end; e += 2) {
            int s0 = e_src[e], s1 = e_src[e + 1];
            float n0 = e_norm[e], n1 = e_norm[e + 1];
            float v0 = xw1[(size_t)s0 * HID + lane];
            float v1 = xw1[(size_t)s1 * HID + lane];
            acc += n0 * v0;
            acc += n1 * v1;
        }
        if (e < end) acc += e_norm[e] * xw1[(size_t)e_src[e] * HID + lane];
        float inv = 1.0f / (float)(cnt[d] + 1);
        acc += inv * xw1[(size_t)d * HID + lane];
        acc += bs;
        h1[(size_t)d * HID + lane] = acc;
        ssum += acc;
        ssq += acc * acc;
    }
    lsum[wave][lane] = ssum;
    lsq[wave][lane] = ssq;
    __syncthreads();
    if (wave == 0) {
        float ts = lsum[0][lane] + lsum[1][lane] + lsum[2][lane] + lsum[3][lane];
        float tq = lsq[0][lane] + lsq[1][lane] + lsq[2][lane] + lsq[3][lane];
        atomicAdd(&sums1[lane], ts);
        atomicAdd(&sums1[64 + lane], tq);
    }
}

// ---------------- gemm2: xw2 = relu(BN1(h1)) @ W2  (BN1 finalize folded in) ----------------
__global__ __launch_bounds__(256) void gemm2_kernel(const float* __restrict__ h1,
                                                    const float* __restrict__ sums1,
                                                    const float* __restrict__ g1,
                                                    const float* __restrict__ be1,
                                                    const float* __restrict__ W2,
                                                    float* __restrict__ xw2) {
    int lane = threadIdx.x & 63;
    int row = blockIdx.x * 4 + (threadIdx.x >> 6);
    if (row >= NN) return;
    int c = lane;
    const float invn = 1.0f / (float)NN;
    float mu = sums1[c] * invn;
    float var = sums1[64 + c] * invn - mu * mu;
    float sc = g1[c] * rsqrtf(var + EPSV);
    float sh = be1[c] - mu * sc;
    float h = h1[(size_t)row * HID + c] * sc + sh;
    h = fmaxf(h, 0.f);
    float p0 = h * W2[c * 2 + 0];
    float p1 = h * W2[c * 2 + 1];
    for (int o = 32; o; o >>= 1) {
        p0 += __shfl_xor(p0, o);
        p1 += __shfl_xor(p1, o);
    }
    if (lane == 0) {
        xw2[(size_t)row * 2 + 0] = p0;
        xw2[(size_t)row * 2 + 1] = p1;
    }
}

// ---------------- agg2: z2 = A_hat @ xw2 + b2, fused BN2 stats ----------------
__global__ __launch_bounds__(256) void agg2_kernel(const float* __restrict__ xw2,
                                                   const int* __restrict__ rowptr,
                                                   const int* __restrict__ e_src,
                                                   const float* __restrict__ e_norm,
                                                   const int* __restrict__ cnt,
                                                   const float* __restrict__ b2,
                                                   float* __restrict__ z2,
                                                   float* __restrict__ sums2) {
    int d = blockIdx.x * 256 + threadIdx.x;
    float z0 = 0.f, z1 = 0.f;
    if (d < NN) {
        int beg = rowptr[d], end = rowptr[d + 1];
        float a0 = 0.f, a1 = 0.f;
        for (int e = beg; e < end; e++) {
            int s = e_src[e];
            float n = e_norm[e];
            a0 += n * xw2[(size_t)s * 2 + 0];
            a1 += n * xw2[(size_t)s * 2 + 1];
        }
        float inv = 1.0f / (float)(cnt[d] + 1);
        a0 += inv * xw2[(size_t)d * 2 + 0];
        a1 += inv * xw2[(size_t)d * 2 + 1];
        z0 = a0 + b2[0];
        z1 = a1 + b2[1];
        z2[(size_t)d * 2 + 0] = z0;
        z2[(size_t)d * 2 + 1] = z1;
    }
    float s0 = z0, s1 = z1, q0 = z0 * z0, q1 = z1 * z1;
    for (int o = 32; o; o >>= 1) {
        s0 += __shfl_xor(s0, o);
        s1 += __shfl_xor(s1, o);
        q0 += __shfl_xor(q0, o);
        q1 += __shfl_xor(q1, o);
    }
    if ((threadIdx.x & 63) == 0) {
        atomicAdd(&sums2[0], s0);
        atomicAdd(&sums2[1], s1);
        atomicAdd(&sums2[2], q0);
        atomicAdd(&sums2[3], q1);
    }
}

// ---------------- decoder: out = BN2(z2) @ Wd + bd  (BN2 finalize folded in) ----------------
__global__ __launch_bounds__(256) void decoder_kernel(const float* __restrict__ z2,
                                                      const float* __restrict__ sums2,
                                                      const float* __restrict__ g2,
                                                      const float* __restrict__ be2,
                                                      const float* __restrict__ Wd,
                                                      const float* __restrict__ bd,
                                                      float* __restrict__ out) {
    int g = blockIdx.x * 256 + threadIdx.x;
    int row = g >> 6;
    int c4 = (g & 63) * 4;
    const float invn = 1.0f / (float)NN;
    float mu0 = sums2[0] * invn, mu1 = sums2[1] * invn;
    float v0 = sums2[2] * invn - mu0 * mu0;
    float v1 = sums2[3] * invn - mu1 * mu1;
    float sc0 = g2[0] * rsqrtf(v0 + EPSV), sh0 = be2[0] - mu0 * sc0;
    float sc1 = g2[1] * rsqrtf(v1 + EPSV), sh1 = be2[1] - mu1 * sc1;
    float zb0 = z2[(size_t)row * 2 + 0] * sc0 + sh0;
    float zb1 = z2[(size_t)row * 2 + 1] * sc1 + sh1;
    float4 w0 = *(const float4*)(Wd + c4);
    float4 w1 = *(const float4*)(Wd + INC + c4);
    float4 bb = *(const float4*)(bd + c4);
    float4 o;
    o.x = zb0 * w0.x + zb1 * w1.x + bb.x;
    o.y = zb0 * w0.y + zb1 * w1.y + bb.y;
    o.z = zb0 * w0.z + zb1 * w1.z + bb.z;
    o.w = zb0 * w0.w + zb1 * w1.w + bb.w;
    *(float4*)(out + (size_t)row * INC + c4) = o;
}

// ---------------- launch ----------------
static inline size_t align256(size_t x) { return (x + 255) & ~(size_t)255; }

extern "C" void kernel_launch(void* const* d_in, const int* in_sizes, int n_in,
                              void* d_out, int out_size, void* d_ws, size_t ws_size,
                              hipStream_t stream) {
    const float* x  = (const float*)d_in[0];
    const int*   ei = (const int*)d_in[1];     // [2, E] int32 (JAX x64 disabled)
    const float* W1 = (const float*)d_in[2];
    const float* b1 = (const float*)d_in[3];
    const float* g1 = (const float*)d_in[4];
    const float* be1 = (const float*)d_in[5];
    const float* W2 = (const float*)d_in[6];
    const float* b2 = (const float*)d_in[7];
    const float* g2 = (const float*)d_in[8];
    const float* be2 = (const float*)d_in[9];
    const float* Wd = (const float*)d_in[10];
    const float* bd = (const float*)d_in[11];
    float* out = (float*)d_out;

    const int* src = ei;
    const int* dst = ei + NE;

    // workspace carve-up (zero region first, one contiguous memset)
    char* ws = (char*)d_ws;
    size_t off = 0;
    int* cnt = (int*)(ws + off);        off = align256(off + NN * 4);
    int* fill = (int*)(ws + off);       off = align256(off + NN * 4);
    float* sums1 = (float*)(ws + off);  off = align256(off + 128 * 4);
    float* sums2 = (float*)(ws + off);  off = align256(off + 4 * 4);
    size_t zero_bytes = off;
    int* rowptr = (int*)(ws + off);     off = align256(off + (NN + 1) * 4);
    int* btot = (int*)(ws + off);       off = align256(off + NBLK * 4);
    int* boff = (int*)(ws + off);       off = align256(off + NBLK * 4);
    int* e_src = (int*)(ws + off);      off = align256(off + (size_t)NE * 4);
    float* e_norm = (float*)(ws + off); off = align256(off + (size_t)NE * 4);
    float* xw1 = (float*)(ws + off);    off = align256(off + (size_t)NN * HID * 4);
    float* h1 = (float*)(ws + off);     off = align256(off + (size_t)NN * HID * 4);
    float* xw2 = (float*)(ws + off);    off = align256(off + (size_t)NN * 2 * 4);
    float* z2 = (float*)(ws + off);     off = align256(off + (size_t)NN * 2 * 4);
    (void)ws_size; (void)in_sizes; (void)n_in; (void)out_size;

    hipMemsetAsync(d_ws, 0, zero_bytes, stream);

    hist_kernel<<<2048, 256, 0, stream>>>(dst, cnt);
    scan_btot_kernel<<<NBLK, 256, 0, stream>>>(cnt, btot);
    scan_boff_kernel<<<1, 128, 0, stream>>>(btot, boff);
    scan_rowptr_kernel<<<NBLK, 256, 0, stream>>>(cnt, boff, rowptr);
    scatter_kernel<<<2048, 256, 0, stream>>>(src, dst, cnt, rowptr, fill, e_src, e_norm);
    gemm1_kernel<<<NN / 16, 256, 0, stream>>>(x, W1, xw1);
    agg1_kernel<<<2048, 256, 0, stream>>>(xw1, rowptr, e_src, e_norm, cnt, b1, h1, sums1);
    gemm2_kernel<<<(NN + 3) / 4, 256, 0, stream>>>(h1, sums1, g1, be1, W2, xw2);
    agg2_kernel<<<(NN + 255) / 256, 256, 0, stream>>>(xw2, rowptr, e_src, e_norm, cnt, b2, z2, sums2);
    decoder_kernel<<<(NN * HID) / 256, 256, 0, stream>>>(z2, sums2, g2, be2, Wd, bd, out);
}

// Round 2
// 788.105 us; speedup vs baseline: 1.2109x; 1.2109x over previous
//
#include <hip/hip_runtime.h>
#include <hip/hip_bf16.h>

#define NN 100000
#define NE 3200000
#define INC 256
#define HID 64
#define OUTC 2
#define EPSV 1e-5f

#define SCAN_CHUNK 1024
#define NBLK ((NN + SCAN_CHUNK - 1) / SCAN_CHUNK)   // 98

// ---------------- histogram: in-degree counts ----------------
__global__ void hist_kernel(const int* __restrict__ dst, int* __restrict__ cnt) {
    int i = blockIdx.x * blockDim.x + threadIdx.x;
    int stride = gridDim.x * blockDim.x;
    for (; i < NE; i += stride) atomicAdd(&cnt[dst[i]], 1);
}

// ---------------- scan step 1: per-chunk totals ----------------
__global__ void scan_btot_kernel(const int* __restrict__ cnt, int* __restrict__ btot) {
    __shared__ int red[4];
    int b = blockIdx.x, t = threadIdx.x;
    int base = b * SCAN_CHUNK;
    int v = 0;
    for (int j = t; j < SCAN_CHUNK; j += 256) {
        int idx = base + j;
        v += (idx < NN) ? cnt[idx] : 0;
    }
    for (int o = 32; o; o >>= 1) v += __shfl_xor(v, o);
    int wave = t >> 6, lane = t & 63;
    if (lane == 0) red[wave] = v;
    __syncthreads();
    if (t == 0) btot[b] = red[0] + red[1] + red[2] + red[3];
}

// ---------------- scan step 2: exclusive scan of chunk totals ----------------
__global__ void scan_boff_kernel(const int* __restrict__ btot, int* __restrict__ boff) {
    __shared__ int wtot[2];
    int t = threadIdx.x;           // 128 threads
    int lane = t & 63, wave = t >> 6;
    int v = (t < NBLK) ? btot[t] : 0;
    int s = v;
    for (int o = 1; o < 64; o <<= 1) {
        int u = __shfl_up(s, o);
        if (lane >= o) s += u;
    }
    if (lane == 63) wtot[wave] = s;
    __syncthreads();
    int add = (wave == 1) ? wtot[0] : 0;
    if (t < NBLK) boff[t] = s - v + add;   // exclusive prefix
}

// ---------------- scan step 3: full rowptr ----------------
__global__ void scan_rowptr_kernel(const int* __restrict__ cnt, const int* __restrict__ boff,
                                   int* __restrict__ rowptr) {
    __shared__ int wsum[4];
    int b = blockIdx.x, t = threadIdx.x;
    int lane = t & 63, wave = t >> 6;
    int idx = b * SCAN_CHUNK + t * 4;
    int c0 = (idx + 0 < NN) ? cnt[idx + 0] : 0;
    int c1 = (idx + 1 < NN) ? cnt[idx + 1] : 0;
    int c2 = (idx + 2 < NN) ? cnt[idx + 2] : 0;
    int c3 = (idx + 3 < NN) ? cnt[idx + 3] : 0;
    int local = c0 + c1 + c2 + c3;
    int s = local;
    for (int o = 1; o < 64; o <<= 1) {
        int u = __shfl_up(s, o);
        if (lane >= o) s += u;
    }
    if (lane == 63) wsum[wave] = s;
    __syncthreads();
    if (t == 0) {
        int run = 0;
        for (int w = 0; w < 4; w++) { int x = wsum[w]; wsum[w] = run; run += x; }
    }
    __syncthreads();
    int start = boff[b] + wsum[wave] + (s - local);
    if (idx + 0 < NN) rowptr[idx + 0] = start;
    if (idx + 1 < NN) rowptr[idx + 1] = start + c0;
    if (idx + 2 < NN) rowptr[idx + 2] = start + c0 + c1;
    if (idx + 3 < NN) rowptr[idx + 3] = start + c0 + c1 + c2;
    if (b == 0 && t == 0) rowptr[NN] = NE;
}

// ---------------- scatter edges into CSR, precompute norm ----------------
__global__ void scatter_kernel(const int* __restrict__ src, const int* __restrict__ dst,
                               const int* __restrict__ cnt, const int* __restrict__ rowptr,
                               int* __restrict__ fill, int* __restrict__ e_src,
                               float* __restrict__ e_norm) {
    int i = blockIdx.x * blockDim.x + threadIdx.x;
    int stride = gridDim.x * blockDim.x;
    for (; i < NE; i += stride) {
        int s = src[i], d = dst[i];
        int pos = rowptr[d] + atomicAdd(&fill[d], 1);
        e_src[pos] = s;
        e_norm[pos] = rsqrtf((float)(cnt[s] + 1) * (float)(cnt[d] + 1));
    }
}

// ---------------- GEMM1: XW1 = x @ W1  ([N,256]@[256,64]) ----------------
// R2 redesign: x tile (32 rows) staged in LDS via coalesced float4 loads;
// W1 read from global (L2-hot, 256B/wave coalesced, lane = out channel).
// Each wave computes 8 rows; x read back from LDS as wave-uniform float2
// broadcasts (conflict-free). 32KB LDS -> 5 blocks/CU occupancy.
#define G1_ROWS 32
__global__ __launch_bounds__(256) void gemm1_kernel(const float* __restrict__ x,
                                                    const float* __restrict__ W1,
                                                    float* __restrict__ xw1) {
    __shared__ float xt[G1_ROWS][INC];   // 32 KB
    int t = threadIdx.x;
    size_t base = (size_t)blockIdx.x * G1_ROWS;
    const float4* xg = (const float4*)(x + base * INC);
    float4* xs = (float4*)xt;
#pragma unroll
    for (int i = 0; i < (G1_ROWS * INC / 4) / 256; i++)
        xs[t + i * 256] = xg[t + i * 256];
    __syncthreads();
    int lane = t & 63;
    int wave = t >> 6;
    int r0 = wave * 8;                    // 8 rows per wave
    float acc[8] = {0.f, 0.f, 0.f, 0.f, 0.f, 0.f, 0.f, 0.f};
    const float* wp = W1 + lane;
#pragma unroll 4
    for (int k = 0; k < INC; k += 2) {
        float w0 = wp[k * HID];
        float w1 = wp[(k + 1) * HID];
#pragma unroll
        for (int r = 0; r < 8; r++) {
            float2 xv = *(const float2*)&xt[r0 + r][k];
            acc[r] += xv.x * w0 + xv.y * w1;
        }
    }
#pragma unroll
    for (int r = 0; r < 8; r++)
        xw1[(base + r0 + r) * HID + lane] = acc[r];
}

// ---------------- agg1: h1 = A_hat @ XW1 + b1, fused BN1 stats ----------------
// wave per dst node, lane = channel; coalesced 256B gathers of XW1[src].
__global__ __launch_bounds__(256) void agg1_kernel(const float* __restrict__ xw1,
                                                   const int* __restrict__ rowptr,
                                                   const int* __restrict__ e_src,
                                                   const float* __restrict__ e_norm,
                                                   const int* __restrict__ cnt,
                                                   const float* __restrict__ b1,
                                                   float* __restrict__ h1,
                                                   float* __restrict__ sums1) {
    __shared__ float lsum[4][64], lsq[4][64];
    int lane = threadIdx.x & 63;
    int wave = threadIdx.x >> 6;
    int wid = blockIdx.x * 4 + wave;
    int wstride = gridDim.x * 4;
    float bs = b1[lane];
    float ssum = 0.f, ssq = 0.f;
    for (int d0 = wid; d0 < NN; d0 += wstride) {
        int d = __builtin_amdgcn_readfirstlane(d0);
        int beg = rowptr[d], end = rowptr[d + 1];
        float acc = 0.f;
        int e = beg;
        for (; e + 1 < end; e += 2) {
            int s0 = e_src[e], s1 = e_src[e + 1];
            float n0 = e_norm[e], n1 = e_norm[e + 1];
            float v0 = xw1[(size_t)s0 * HID + lane];
            float v1 = xw1[(size_t)s1 * HID + lane];
            acc += n0 * v0;
            acc += n1 * v1;
        }
        if (e < end) acc += e_norm[e] * xw1[(size_t)e_src[e] * HID + lane];
        float inv = 1.0f / (float)(cnt[d] + 1);
        acc += inv * xw1[(size_t)d * HID + lane];
        acc += bs;
        h1[(size_t)d * HID + lane] = acc;
        ssum += acc;
        ssq += acc * acc;
    }
    lsum[wave][lane] = ssum;
    lsq[wave][lane] = ssq;
    __syncthreads();
    if (wave == 0) {
        float ts = lsum[0][lane] + lsum[1][lane] + lsum[2][lane] + lsum[3][lane];
        float tq = lsq[0][lane] + lsq[1][lane] + lsq[2][lane] + lsq[3][lane];
        atomicAdd(&sums1[lane], ts);
        atomicAdd(&sums1[64 + lane], tq);
    }
}

// ---------------- gemm2: xw2 = relu(BN1(h1)) @ W2  (BN1 finalize folded in) ----------------
__global__ __launch_bounds__(256) void gemm2_kernel(const float* __restrict__ h1,
                                                    const float* __restrict__ sums1,
                                                    const float* __restrict__ g1,
                                                    const float* __restrict__ be1,
                                                    const float* __restrict__ W2,
                                                    float* __restrict__ xw2) {
    int lane = threadIdx.x & 63;
    int row = blockIdx.x * 4 + (threadIdx.x >> 6);
    if (row >= NN) return;
    int c = lane;
    const float invn = 1.0f / (float)NN;
    float mu = sums1[c] * invn;
    float var = sums1[64 + c] * invn - mu * mu;
    float sc = g1[c] * rsqrtf(var + EPSV);
    float sh = be1[c] - mu * sc;
    float h = h1[(size_t)row * HID + c] * sc + sh;
    h = fmaxf(h, 0.f);
    float p0 = h * W2[c * 2 + 0];
    float p1 = h * W2[c * 2 + 1];
    for (int o = 32; o; o >>= 1) {
        p0 += __shfl_xor(p0, o);
        p1 += __shfl_xor(p1, o);
    }
    if (lane == 0) {
        xw2[(size_t)row * 2 + 0] = p0;
        xw2[(size_t)row * 2 + 1] = p1;
    }
}

// ---------------- agg2: z2 = A_hat @ xw2 + b2, fused BN2 stats ----------------
__global__ __launch_bounds__(256) void agg2_kernel(const float* __restrict__ xw2,
                                                   const int* __restrict__ rowptr,
                                                   const int* __restrict__ e_src,
                                                   const float* __restrict__ e_norm,
                                                   const int* __restrict__ cnt,
                                                   const float* __restrict__ b2,
                                                   float* __restrict__ z2,
                                                   float* __restrict__ sums2) {
    int d = blockIdx.x * 256 + threadIdx.x;
    float z0 = 0.f, z1 = 0.f;
    if (d < NN) {
        int beg = rowptr[d], end = rowptr[d + 1];
        float a0 = 0.f, a1 = 0.f;
        for (int e = beg; e < end; e++) {
            int s = e_src[e];
            float n = e_norm[e];
            a0 += n * xw2[(size_t)s * 2 + 0];
            a1 += n * xw2[(size_t)s * 2 + 1];
        }
        float inv = 1.0f / (float)(cnt[d] + 1);
        a0 += inv * xw2[(size_t)d * 2 + 0];
        a1 += inv * xw2[(size_t)d * 2 + 1];
        z0 = a0 + b2[0];
        z1 = a1 + b2[1];
        z2[(size_t)d * 2 + 0] = z0;
        z2[(size_t)d * 2 + 1] = z1;
    }
    float s0 = z0, s1 = z1, q0 = z0 * z0, q1 = z1 * z1;
    for (int o = 32; o; o >>= 1) {
        s0 += __shfl_xor(s0, o);
        s1 += __shfl_xor(s1, o);
        q0 += __shfl_xor(q0, o);
        q1 += __shfl_xor(q1, o);
    }
    if ((threadIdx.x & 63) == 0) {
        atomicAdd(&sums2[0], s0);
        atomicAdd(&sums2[1], s1);
        atomicAdd(&sums2[2], q0);
        atomicAdd(&sums2[3], q1);
    }
}

// ---------------- decoder: out = BN2(z2) @ Wd + bd  (BN2 finalize folded in) ----------------
__global__ __launch_bounds__(256) void decoder_kernel(const float* __restrict__ z2,
                                                      const float* __restrict__ sums2,
                                                      const float* __restrict__ g2,
                                                      const float* __restrict__ be2,
                                                      const float* __restrict__ Wd,
                                                      const float* __restrict__ bd,
                                                      float* __restrict__ out) {
    int g = blockIdx.x * 256 + threadIdx.x;
    int row = g >> 6;
    int c4 = (g & 63) * 4;
    const float invn = 1.0f / (float)NN;
    float mu0 = sums2[0] * invn, mu1 = sums2[1] * invn;
    float v0 = sums2[2] * invn - mu0 * mu0;
    float v1 = sums2[3] * invn - mu1 * mu1;
    float sc0 = g2[0] * rsqrtf(v0 + EPSV), sh0 = be2[0] - mu0 * sc0;
    float sc1 = g2[1] * rsqrtf(v1 + EPSV), sh1 = be2[1] - mu1 * sc1;
    float zb0 = z2[(size_t)row * 2 + 0] * sc0 + sh0;
    float zb1 = z2[(size_t)row * 2 + 1] * sc1 + sh1;
    float4 w0 = *(const float4*)(Wd + c4);
    float4 w1 = *(const float4*)(Wd + INC + c4);
    float4 bb = *(const float4*)(bd + c4);
    float4 o;
    o.x = zb0 * w0.x + zb1 * w1.x + bb.x;
    o.y = zb0 * w0.y + zb1 * w1.y + bb.y;
    o.z = zb0 * w0.z + zb1 * w1.z + bb.z;
    o.w = zb0 * w0.w + zb1 * w1.w + bb.w;
    *(float4*)(out + (size_t)row * INC + c4) = o;
}

// ---------------- launch ----------------
static inline size_t align256(size_t x) { return (x + 255) & ~(size_t)255; }

extern "C" void kernel_launch(void* const* d_in, const int* in_sizes, int n_in,
                              void* d_out, int out_size, void* d_ws, size_t ws_size,
                              hipStream_t stream) {
    const float* x  = (const float*)d_in[0];
    const int*   ei = (const int*)d_in[1];     // [2, E] int32
    const float* W1 = (const float*)d_in[2];
    const float* b1 = (const float*)d_in[3];
    const float* g1 = (const float*)d_in[4];
    const float* be1 = (const float*)d_in[5];
    const float* W2 = (const float*)d_in[6];
    const float* b2 = (const float*)d_in[7];
    const float* g2 = (const float*)d_in[8];
    const float* be2 = (const float*)d_in[9];
    const float* Wd = (const float*)d_in[10];
    const float* bd = (const float*)d_in[11];
    float* out = (float*)d_out;

    const int* src = ei;
    const int* dst = ei + NE;

    char* ws = (char*)d_ws;
    size_t off = 0;
    int* cnt = (int*)(ws + off);        off = align256(off + NN * 4);
    int* fill = (int*)(ws + off);       off = align256(off + NN * 4);
    float* sums1 = (float*)(ws + off);  off = align256(off + 128 * 4);
    float* sums2 = (float*)(ws + off);  off = align256(off + 4 * 4);
    size_t zero_bytes = off;
    int* rowptr = (int*)(ws + off);     off = align256(off + (NN + 1) * 4);
    int* btot = (int*)(ws + off);       off = align256(off + NBLK * 4);
    int* boff = (int*)(ws + off);       off = align256(off + NBLK * 4);
    int* e_src = (int*)(ws + off);      off = align256(off + (size_t)NE * 4);
    float* e_norm = (float*)(ws + off); off = align256(off + (size_t)NE * 4);
    float* xw1 = (float*)(ws + off);    off = align256(off + (size_t)NN * HID * 4);
    float* h1 = (float*)(ws + off);     off = align256(off + (size_t)NN * HID * 4);
    float* xw2 = (float*)(ws + off);    off = align256(off + (size_t)NN * 2 * 4);
    float* z2 = (float*)(ws + off);     off = align256(off + (size_t)NN * 2 * 4);
    (void)ws_size; (void)in_sizes; (void)n_in; (void)out_size;

    hipMemsetAsync(d_ws, 0, zero_bytes, stream);

    hist_kernel<<<2048, 256, 0, stream>>>(dst, cnt);
    scan_btot_kernel<<<NBLK, 256, 0, stream>>>(cnt, btot);
    scan_boff_kernel<<<1, 128, 0, stream>>>(btot, boff);
    scan_rowptr_kernel<<<NBLK, 256, 0, stream>>>(cnt, boff, rowptr);
    scatter_kernel<<<2048, 256, 0, stream>>>(src, dst, cnt, rowptr, fill, e_src, e_norm);
    gemm1_kernel<<<NN / G1_ROWS, 256, 0, stream>>>(x, W1, xw1);
    agg1_kernel<<<2048, 256, 0, stream>>>(xw1, rowptr, e_src, e_norm, cnt, b1, h1, sums1);
    gemm2_kernel<<<(NN + 3) / 4, 256, 0, stream>>>(h1, sums1, g1, be1, W2, xw2);
    agg2_kernel<<<(NN + 255) / 256, 256, 0, stream>>>(xw2, rowptr, e_src, e_norm, cnt, b2, z2, sums2);
    decoder_kernel<<<(NN * HID) / 256, 256, 0, stream>>>(z2, sums2, g2, be2, Wd, bd, out);
}

// Round 3
// 663.063 us; speedup vs baseline: 1.4393x; 1.1886x over previous
//
#include <hip/hip_runtime.h>
#include <hip/hip_bf16.h>

#define NN 100000
#define NE 3200000
#define INC 256
#define HID 64
#define OUTC 2
#define EPSV 1e-5f

#define SCAN_CHUNK 1024
#define NBLK ((NN + SCAN_CHUNK - 1) / SCAN_CHUNK)   // 98
#define NCOHORT 8
#define COHORT_NN (NN / NCOHORT)                     // 12500 exactly

// ---------------- histogram: in-degree counts (cohort = dst-range = XCD-local atomics) ----------------
__global__ void hist_kernel(const int* __restrict__ dst, int* __restrict__ cnt) {
    int cohort = blockIdx.x & (NCOHORT - 1);
    int lo = cohort * COHORT_NN, hi = lo + COHORT_NN;
    int i = (blockIdx.x >> 3) * blockDim.x + threadIdx.x;
    int stride = (gridDim.x >> 3) * blockDim.x;
    for (; i < NE; i += stride) {
        int d = dst[i];
        if (d >= lo && d < hi) atomicAdd(&cnt[d], 1);
    }
}

// ---------------- scan step 1: per-chunk totals ----------------
__global__ void scan_btot_kernel(const int* __restrict__ cnt, int* __restrict__ btot) {
    __shared__ int red[4];
    int b = blockIdx.x, t = threadIdx.x;
    int base = b * SCAN_CHUNK;
    int v = 0;
    for (int j = t; j < SCAN_CHUNK; j += 256) {
        int idx = base + j;
        v += (idx < NN) ? cnt[idx] : 0;
    }
    for (int o = 32; o; o >>= 1) v += __shfl_xor(v, o);
    int wave = t >> 6, lane = t & 63;
    if (lane == 0) red[wave] = v;
    __syncthreads();
    if (t == 0) btot[b] = red[0] + red[1] + red[2] + red[3];
}

// ---------------- scan step 2: exclusive scan of chunk totals ----------------
__global__ void scan_boff_kernel(const int* __restrict__ btot, int* __restrict__ boff) {
    __shared__ int wtot[2];
    int t = threadIdx.x;           // 128 threads
    int lane = t & 63, wave = t >> 6;
    int v = (t < NBLK) ? btot[t] : 0;
    int s = v;
    for (int o = 1; o < 64; o <<= 1) {
        int u = __shfl_up(s, o);
        if (lane >= o) s += u;
    }
    if (lane == 63) wtot[wave] = s;
    __syncthreads();
    int add = (wave == 1) ? wtot[0] : 0;
    if (t < NBLK) boff[t] = s - v + add;   // exclusive prefix
}

// ---------------- scan step 3: full rowptr + dinv ----------------
__global__ void scan_rowptr_kernel(const int* __restrict__ cnt, const int* __restrict__ boff,
                                   int* __restrict__ rowptr, float* __restrict__ dinv) {
    __shared__ int wsum[4];
    int b = blockIdx.x, t = threadIdx.x;
    int lane = t & 63, wave = t >> 6;
    int idx = b * SCAN_CHUNK + t * 4;
    int c0 = (idx + 0 < NN) ? cnt[idx + 0] : 0;
    int c1 = (idx + 1 < NN) ? cnt[idx + 1] : 0;
    int c2 = (idx + 2 < NN) ? cnt[idx + 2] : 0;
    int c3 = (idx + 3 < NN) ? cnt[idx + 3] : 0;
    int local = c0 + c1 + c2 + c3;
    int s = local;
    for (int o = 1; o < 64; o <<= 1) {
        int u = __shfl_up(s, o);
        if (lane >= o) s += u;
    }
    if (lane == 63) wsum[wave] = s;
    __syncthreads();
    if (t == 0) {
        int run = 0;
        for (int w = 0; w < 4; w++) { int x = wsum[w]; wsum[w] = run; run += x; }
    }
    __syncthreads();
    int start = boff[b] + wsum[wave] + (s - local);
    if (idx + 0 < NN) { rowptr[idx + 0] = start;                dinv[idx + 0] = rsqrtf((float)(c0 + 1)); }
    if (idx + 1 < NN) { rowptr[idx + 1] = start + c0;           dinv[idx + 1] = rsqrtf((float)(c1 + 1)); }
    if (idx + 2 < NN) { rowptr[idx + 2] = start + c0 + c1;      dinv[idx + 2] = rsqrtf((float)(c2 + 1)); }
    if (idx + 3 < NN) { rowptr[idx + 3] = start + c0 + c1 + c2; dinv[idx + 3] = rsqrtf((float)(c3 + 1)); }
    if (b == 0 && t == 0) rowptr[NN] = NE;
}

// ---------------- scatter edges into CSR (cohort dst-range -> L2-local writes) ----------------
__global__ void scatter_kernel(const int* __restrict__ src, const int* __restrict__ dst,
                               const int* __restrict__ rowptr, int* __restrict__ fill,
                               int* __restrict__ e_src) {
    int cohort = blockIdx.x & (NCOHORT - 1);
    int lo = cohort * COHORT_NN, hi = lo + COHORT_NN;
    int i = (blockIdx.x >> 3) * blockDim.x + threadIdx.x;
    int stride = (gridDim.x >> 3) * blockDim.x;
    for (; i < NE; i += stride) {
        int d = dst[i];
        if (d >= lo && d < hi) {
            int s = src[i];
            int pos = rowptr[d] + atomicAdd(&fill[d], 1);
            e_src[pos] = s;
        }
    }
}

// ---------------- GEMM1: xw1' = dinv .* (x @ W1)  ([N,256]@[256,64]) ----------------
// x tile (32 rows) staged in LDS via coalesced float4 loads; W1 from global
// (L2-hot, lane = out channel). dinv row-scale folded into the epilogue.
#define G1_ROWS 32
__global__ __launch_bounds__(256) void gemm1_kernel(const float* __restrict__ x,
                                                    const float* __restrict__ W1,
                                                    const float* __restrict__ dinv,
                                                    float* __restrict__ xw1) {
    __shared__ float xt[G1_ROWS][INC];   // 32 KB
    int t = threadIdx.x;
    size_t base = (size_t)blockIdx.x * G1_ROWS;
    const float4* xg = (const float4*)(x + base * INC);
    float4* xs = (float4*)xt;
#pragma unroll
    for (int i = 0; i < (G1_ROWS * INC / 4) / 256; i++)
        xs[t + i * 256] = xg[t + i * 256];
    __syncthreads();
    int lane = t & 63;
    int wave = t >> 6;
    int r0 = wave * 8;                    // 8 rows per wave
    float acc[8] = {0.f, 0.f, 0.f, 0.f, 0.f, 0.f, 0.f, 0.f};
    const float* wp = W1 + lane;
#pragma unroll 4
    for (int k = 0; k < INC; k += 2) {
        float w0 = wp[k * HID];
        float w1 = wp[(k + 1) * HID];
#pragma unroll
        for (int r = 0; r < 8; r++) {
            float2 xv = *(const float2*)&xt[r0 + r][k];
            acc[r] += xv.x * w0 + xv.y * w1;
        }
    }
#pragma unroll
    for (int r = 0; r < 8; r++)
        xw1[(base + r0 + r) * HID + lane] = acc[r] * dinv[base + r0 + r];
}

// ---------------- agg1: h1 = dinv_d*(sum_edges xw1'[s] + xw1'[d]) + b1, fused BN1 stats ----------------
// wave per dst node, lane = channel; coalesced 256B gathers of xw1'[src].
__global__ __launch_bounds__(256) void agg1_kernel(const float* __restrict__ xw1,
                                                   const int* __restrict__ rowptr,
                                                   const int* __restrict__ e_src,
                                                   const float* __restrict__ dinv,
                                                   const float* __restrict__ b1,
                                                   float* __restrict__ h1,
                                                   float* __restrict__ sums1) {
    __shared__ float lsum[4][64], lsq[4][64];
    int lane = threadIdx.x & 63;
    int wave = threadIdx.x >> 6;
    int wid = blockIdx.x * 4 + wave;
    int wstride = gridDim.x * 4;
    float bs = b1[lane];
    float ssum = 0.f, ssq = 0.f;
    for (int d0 = wid; d0 < NN; d0 += wstride) {
        int d = __builtin_amdgcn_readfirstlane(d0);
        int beg = rowptr[d], end = rowptr[d + 1];
        float acc = 0.f;
        int e = beg;
        for (; e + 3 < end; e += 4) {
            int s0 = e_src[e], s1 = e_src[e + 1], s2 = e_src[e + 2], s3 = e_src[e + 3];
            float v0 = xw1[(size_t)s0 * HID + lane];
            float v1 = xw1[(size_t)s1 * HID + lane];
            float v2 = xw1[(size_t)s2 * HID + lane];
            float v3 = xw1[(size_t)s3 * HID + lane];
            acc += v0 + v1 + v2 + v3;
        }
        for (; e < end; e++) acc += xw1[(size_t)e_src[e] * HID + lane];
        acc += xw1[(size_t)d * HID + lane];     // self-loop (already dinv-scaled)
        float h = acc * dinv[d] + bs;
        h1[(size_t)d * HID + lane] = h;
        ssum += h;
        ssq += h * h;
    }
    lsum[wave][lane] = ssum;
    lsq[wave][lane] = ssq;
    __syncthreads();
    if (wave == 0) {
        float ts = lsum[0][lane] + lsum[1][lane] + lsum[2][lane] + lsum[3][lane];
        float tq = lsq[0][lane] + lsq[1][lane] + lsq[2][lane] + lsq[3][lane];
        atomicAdd(&sums1[lane], ts);
        atomicAdd(&sums1[64 + lane], tq);
    }
}

// ---------------- gemm2: xw2' = dinv .* (relu(BN1(h1)) @ W2) ----------------
__global__ __launch_bounds__(256) void gemm2_kernel(const float* __restrict__ h1,
                                                    const float* __restrict__ sums1,
                                                    const float* __restrict__ g1,
                                                    const float* __restrict__ be1,
                                                    const float* __restrict__ W2,
                                                    const float* __restrict__ dinv,
                                                    float* __restrict__ xw2) {
    int lane = threadIdx.x & 63;
    int row = blockIdx.x * 4 + (threadIdx.x >> 6);
    if (row >= NN) return;
    int c = lane;
    const float invn = 1.0f / (float)NN;
    float mu = sums1[c] * invn;
    float var = sums1[64 + c] * invn - mu * mu;
    float sc = g1[c] * rsqrtf(var + EPSV);
    float sh = be1[c] - mu * sc;
    float h = h1[(size_t)row * HID + c] * sc + sh;
    h = fmaxf(h, 0.f);
    float p0 = h * W2[c * 2 + 0];
    float p1 = h * W2[c * 2 + 1];
    for (int o = 32; o; o >>= 1) {
        p0 += __shfl_xor(p0, o);
        p1 += __shfl_xor(p1, o);
    }
    if (lane == 0) {
        float dv = dinv[row];
        xw2[(size_t)row * 2 + 0] = p0 * dv;
        xw2[(size_t)row * 2 + 1] = p1 * dv;
    }
}

// ---------------- agg2: z2 = dinv_d*(sum xw2'[s] + xw2'[d]) + b2, fused BN2 stats ----------------
__global__ __launch_bounds__(256) void agg2_kernel(const float* __restrict__ xw2,
                                                   const int* __restrict__ rowptr,
                                                   const int* __restrict__ e_src,
                                                   const float* __restrict__ dinv,
                                                   const float* __restrict__ b2,
                                                   float* __restrict__ z2,
                                                   float* __restrict__ sums2) {
    int d = blockIdx.x * 256 + threadIdx.x;
    float z0 = 0.f, z1 = 0.f;
    if (d < NN) {
        int beg = rowptr[d], end = rowptr[d + 1];
        float a0 = 0.f, a1 = 0.f;
        for (int e = beg; e < end; e++) {
            int s = e_src[e];
            a0 += xw2[(size_t)s * 2 + 0];
            a1 += xw2[(size_t)s * 2 + 1];
        }
        a0 += xw2[(size_t)d * 2 + 0];
        a1 += xw2[(size_t)d * 2 + 1];
        float dv = dinv[d];
        z0 = a0 * dv + b2[0];
        z1 = a1 * dv + b2[1];
        z2[(size_t)d * 2 + 0] = z0;
        z2[(size_t)d * 2 + 1] = z1;
    }
    float s0 = z0, s1 = z1, q0 = z0 * z0, q1 = z1 * z1;
    for (int o = 32; o; o >>= 1) {
        s0 += __shfl_xor(s0, o);
        s1 += __shfl_xor(s1, o);
        q0 += __shfl_xor(q0, o);
        q1 += __shfl_xor(q1, o);
    }
    if ((threadIdx.x & 63) == 0) {
        atomicAdd(&sums2[0], s0);
        atomicAdd(&sums2[1], s1);
        atomicAdd(&sums2[2], q0);
        atomicAdd(&sums2[3], q1);
    }
}

// ---------------- decoder: out = BN2(z2) @ Wd + bd  (BN2 finalize folded in) ----------------
__global__ __launch_bounds__(256) void decoder_kernel(const float* __restrict__ z2,
                                                      const float* __restrict__ sums2,
                                                      const float* __restrict__ g2,
                                                      const float* __restrict__ be2,
                                                      const float* __restrict__ Wd,
                                                      const float* __restrict__ bd,
                                                      float* __restrict__ out) {
    int g = blockIdx.x * 256 + threadIdx.x;
    int row = g >> 6;
    int c4 = (g & 63) * 4;
    const float invn = 1.0f / (float)NN;
    float mu0 = sums2[0] * invn, mu1 = sums2[1] * invn;
    float v0 = sums2[2] * invn - mu0 * mu0;
    float v1 = sums2[3] * invn - mu1 * mu1;
    float sc0 = g2[0] * rsqrtf(v0 + EPSV), sh0 = be2[0] - mu0 * sc0;
    float sc1 = g2[1] * rsqrtf(v1 + EPSV), sh1 = be2[1] - mu1 * sc1;
    float zb0 = z2[(size_t)row * 2 + 0] * sc0 + sh0;
    float zb1 = z2[(size_t)row * 2 + 1] * sc1 + sh1;
    float4 w0 = *(const float4*)(Wd + c4);
    float4 w1 = *(const float4*)(Wd + INC + c4);
    float4 bb = *(const float4*)(bd + c4);
    float4 o;
    o.x = zb0 * w0.x + zb1 * w1.x + bb.x;
    o.y = zb0 * w0.y + zb1 * w1.y + bb.y;
    o.z = zb0 * w0.z + zb1 * w1.z + bb.z;
    o.w = zb0 * w0.w + zb1 * w1.w + bb.w;
    *(float4*)(out + (size_t)row * INC + c4) = o;
}

// ---------------- launch ----------------
static inline size_t align256(size_t x) { return (x + 255) & ~(size_t)255; }

extern "C" void kernel_launch(void* const* d_in, const int* in_sizes, int n_in,
                              void* d_out, int out_size, void* d_ws, size_t ws_size,
                              hipStream_t stream) {
    const float* x  = (const float*)d_in[0];
    const int*   ei = (const int*)d_in[1];     // [2, E] int32
    const float* W1 = (const float*)d_in[2];
    const float* b1 = (const float*)d_in[3];
    const float* g1 = (const float*)d_in[4];
    const float* be1 = (const float*)d_in[5];
    const float* W2 = (const float*)d_in[6];
    const float* b2 = (const float*)d_in[7];
    const float* g2 = (const float*)d_in[8];
    const float* be2 = (const float*)d_in[9];
    const float* Wd = (const float*)d_in[10];
    const float* bd = (const float*)d_in[11];
    float* out = (float*)d_out;

    const int* src = ei;
    const int* dst = ei + NE;

    char* ws = (char*)d_ws;
    size_t off = 0;
    int* cnt = (int*)(ws + off);        off = align256(off + NN * 4);
    int* fill = (int*)(ws + off);       off = align256(off + NN * 4);
    float* sums1 = (float*)(ws + off);  off = align256(off + 128 * 4);
    float* sums2 = (float*)(ws + off);  off = align256(off + 4 * 4);
    size_t zero_bytes = off;
    int* rowptr = (int*)(ws + off);     off = align256(off + (NN + 1) * 4);
    float* dinv = (float*)(ws + off);   off = align256(off + NN * 4);
    int* btot = (int*)(ws + off);       off = align256(off + NBLK * 4);
    int* boff = (int*)(ws + off);       off = align256(off + NBLK * 4);
    int* e_src = (int*)(ws + off);      off = align256(off + (size_t)NE * 4);
    float* xw1 = (float*)(ws + off);    off = align256(off + (size_t)NN * HID * 4);
    float* h1 = (float*)(ws + off);     off = align256(off + (size_t)NN * HID * 4);
    float* xw2 = (float*)(ws + off);    off = align256(off + (size_t)NN * 2 * 4);
    float* z2 = (float*)(ws + off);     off = align256(off + (size_t)NN * 2 * 4);
    (void)ws_size; (void)in_sizes; (void)n_in; (void)out_size;

    hipMemsetAsync(d_ws, 0, zero_bytes, stream);

    hist_kernel<<<2048, 256, 0, stream>>>(dst, cnt);
    scan_btot_kernel<<<NBLK, 256, 0, stream>>>(cnt, btot);
    scan_boff_kernel<<<1, 128, 0, stream>>>(btot, boff);
    scan_rowptr_kernel<<<NBLK, 256, 0, stream>>>(cnt, boff, rowptr, dinv);
    scatter_kernel<<<2048, 256, 0, stream>>>(src, dst, rowptr, fill, e_src);
    gemm1_kernel<<<NN / G1_ROWS, 256, 0, stream>>>(x, W1, dinv, xw1);
    agg1_kernel<<<2048, 256, 0, stream>>>(xw1, rowptr, e_src, dinv, b1, h1, sums1);
    gemm2_kernel<<<(NN + 3) / 4, 256, 0, stream>>>(h1, sums1, g1, be1, W2, dinv, xw2);
    agg2_kernel<<<(NN + 255) / 256, 256, 0, stream>>>(xw2, rowptr, e_src, dinv, b2, z2, sums2);
    decoder_kernel<<<(NN * HID) / 256, 256, 0, stream>>>(z2, sums2, g2, be2, Wd, bd, out);
}

// Round 4
// 614.633 us; speedup vs baseline: 1.5527x; 1.0788x over previous
//
#include <hip/hip_runtime.h>
#include <hip/hip_bf16.h>

#define NN 100000
#define NE 3200000
#define INC 256
#define HID 64
#define OUTC 2
#define EPSV 1e-5f

#define SCAN_CHUNK 1024
#define NBLK ((NN + SCAN_CHUNK - 1) / SCAN_CHUNK)   // 98
#define NCOHORT 8
#define COHORT_NN (NN / NCOHORT)                     // 12500 exactly

static __device__ __forceinline__ float bf2f(unsigned short u) {
    return __uint_as_float((unsigned)u << 16);
}

// ---------------- histogram: in-degree counts (cohort = dst-range = XCD-local atomics) ----------------
__global__ void hist_kernel(const int* __restrict__ dst, int* __restrict__ cnt) {
    int cohort = blockIdx.x & (NCOHORT - 1);
    int lo = cohort * COHORT_NN, hi = lo + COHORT_NN;
    int i = (blockIdx.x >> 3) * blockDim.x + threadIdx.x;
    int stride = (gridDim.x >> 3) * blockDim.x;
    for (; i < NE; i += stride) {
        int d = dst[i];
        if (d >= lo && d < hi) atomicAdd(&cnt[d], 1);
    }
}

// ---------------- scan step 1: per-chunk totals ----------------
__global__ void scan_btot_kernel(const int* __restrict__ cnt, int* __restrict__ btot) {
    __shared__ int red[4];
    int b = blockIdx.x, t = threadIdx.x;
    int base = b * SCAN_CHUNK;
    int v = 0;
    for (int j = t; j < SCAN_CHUNK; j += 256) {
        int idx = base + j;
        v += (idx < NN) ? cnt[idx] : 0;
    }
    for (int o = 32; o; o >>= 1) v += __shfl_xor(v, o);
    int wave = t >> 6, lane = t & 63;
    if (lane == 0) red[wave] = v;
    __syncthreads();
    if (t == 0) btot[b] = red[0] + red[1] + red[2] + red[3];
}

// ---------------- scan step 2: exclusive scan of chunk totals ----------------
__global__ void scan_boff_kernel(const int* __restrict__ btot, int* __restrict__ boff) {
    __shared__ int wtot[2];
    int t = threadIdx.x;           // 128 threads
    int lane = t & 63, wave = t >> 6;
    int v = (t < NBLK) ? btot[t] : 0;
    int s = v;
    for (int o = 1; o < 64; o <<= 1) {
        int u = __shfl_up(s, o);
        if (lane >= o) s += u;
    }
    if (lane == 63) wtot[wave] = s;
    __syncthreads();
    int add = (wave == 1) ? wtot[0] : 0;
    if (t < NBLK) boff[t] = s - v + add;   // exclusive prefix
}

// ---------------- scan step 3: full rowptr + dinv ----------------
__global__ void scan_rowptr_kernel(const int* __restrict__ cnt, const int* __restrict__ boff,
                                   int* __restrict__ rowptr, float* __restrict__ dinv) {
    __shared__ int wsum[4];
    int b = blockIdx.x, t = threadIdx.x;
    int lane = t & 63, wave = t >> 6;
    int idx = b * SCAN_CHUNK + t * 4;
    int c0 = (idx + 0 < NN) ? cnt[idx + 0] : 0;
    int c1 = (idx + 1 < NN) ? cnt[idx + 1] : 0;
    int c2 = (idx + 2 < NN) ? cnt[idx + 2] : 0;
    int c3 = (idx + 3 < NN) ? cnt[idx + 3] : 0;
    int local = c0 + c1 + c2 + c3;
    int s = local;
    for (int o = 1; o < 64; o <<= 1) {
        int u = __shfl_up(s, o);
        if (lane >= o) s += u;
    }
    if (lane == 63) wsum[wave] = s;
    __syncthreads();
    if (t == 0) {
        int run = 0;
        for (int w = 0; w < 4; w++) { int x = wsum[w]; wsum[w] = run; run += x; }
    }
    __syncthreads();
    int start = boff[b] + wsum[wave] + (s - local);
    if (idx + 0 < NN) { rowptr[idx + 0] = start;                dinv[idx + 0] = rsqrtf((float)(c0 + 1)); }
    if (idx + 1 < NN) { rowptr[idx + 1] = start + c0;           dinv[idx + 1] = rsqrtf((float)(c1 + 1)); }
    if (idx + 2 < NN) { rowptr[idx + 2] = start + c0 + c1;      dinv[idx + 2] = rsqrtf((float)(c2 + 1)); }
    if (idx + 3 < NN) { rowptr[idx + 3] = start + c0 + c1 + c2; dinv[idx + 3] = rsqrtf((float)(c3 + 1)); }
    if (b == 0 && t == 0) rowptr[NN] = NE;
}

// ---------------- scatter edges into CSR (cohort dst-range -> L2-local writes) ----------------
__global__ void scatter_kernel(const int* __restrict__ src, const int* __restrict__ dst,
                               const int* __restrict__ rowptr, int* __restrict__ fill,
                               int* __restrict__ e_src) {
    int cohort = blockIdx.x & (NCOHORT - 1);
    int lo = cohort * COHORT_NN, hi = lo + COHORT_NN;
    int i = (blockIdx.x >> 3) * blockDim.x + threadIdx.x;
    int stride = (gridDim.x >> 3) * blockDim.x;
    for (; i < NE; i += stride) {
        int d = dst[i];
        if (d >= lo && d < hi) {
            int s = src[i];
            int pos = rowptr[d] + atomicAdd(&fill[d], 1);
            e_src[pos] = s;
        }
    }
}

// ---------------- GEMM1: xw1b = bf16( dinv .* (x @ W1) )  ([N,256]@[256,64]) ----------------
// x tile (32 rows) staged in LDS via coalesced float4 loads; W1 from global
// (L2-hot, lane = out channel). dinv row-scale + bf16 convert in the epilogue.
#define G1_ROWS 32
__global__ __launch_bounds__(256) void gemm1_kernel(const float* __restrict__ x,
                                                    const float* __restrict__ W1,
                                                    const float* __restrict__ dinv,
                                                    unsigned short* __restrict__ xw1b) {
    __shared__ float xt[G1_ROWS][INC];   // 32 KB
    int t = threadIdx.x;
    size_t base = (size_t)blockIdx.x * G1_ROWS;
    const float4* xg = (const float4*)(x + base * INC);
    float4* xs = (float4*)xt;
#pragma unroll
    for (int i = 0; i < (G1_ROWS * INC / 4) / 256; i++)
        xs[t + i * 256] = xg[t + i * 256];
    __syncthreads();
    int lane = t & 63;
    int wave = t >> 6;
    int r0 = wave * 8;                    // 8 rows per wave
    float acc[8] = {0.f, 0.f, 0.f, 0.f, 0.f, 0.f, 0.f, 0.f};
    const float* wp = W1 + lane;
#pragma unroll 4
    for (int k = 0; k < INC; k += 2) {
        float w0 = wp[k * HID];
        float w1 = wp[(k + 1) * HID];
#pragma unroll
        for (int r = 0; r < 8; r++) {
            float2 xv = *(const float2*)&xt[r0 + r][k];
            acc[r] += xv.x * w0 + xv.y * w1;
        }
    }
#pragma unroll
    for (int r = 0; r < 8; r++) {
        float v = acc[r] * dinv[base + r0 + r];
        __hip_bfloat16 hb = __float2bfloat16(v);   // RNE
        xw1b[(base + r0 + r) * HID + lane] = *(unsigned short*)&hb;
    }
}

// ---------------- agg1: h1 = dinv_d*(sum_edges xw1'[s] + xw1'[d]) + b1, fused BN1 stats ----------------
// wave per dst node; halves of the wave gather two 128B bf16 rows per instr.
// lane covers 2 channels (ushort2); halves combined via shfl_xor(32).
__global__ __launch_bounds__(256) void agg1_kernel(const unsigned short* __restrict__ xw1b,
                                                   const int* __restrict__ rowptr,
                                                   const int* __restrict__ e_src,
                                                   const float* __restrict__ dinv,
                                                   const float* __restrict__ b1,
                                                   float* __restrict__ h1,
                                                   float* __restrict__ sums1) {
    __shared__ float lsum[4][64], lsq[4][64];
    int lane = threadIdx.x & 63;
    int wave = threadIdx.x >> 6;
    int half = lane >> 5;
    int cp = lane & 31;                     // channel pair: channels 2cp, 2cp+1
    int wid = blockIdx.x * 4 + wave;
    int wstride = gridDim.x * 4;
    float bb0 = b1[2 * cp], bb1 = b1[2 * cp + 1];
    float ssum0 = 0.f, ssq0 = 0.f, ssum1 = 0.f, ssq1 = 0.f;
    const ushort2* xw = (const ushort2*)xw1b;   // row = 32 ushort2
    for (int d0 = wid; d0 < NN; d0 += wstride) {
        int d = __builtin_amdgcn_readfirstlane(d0);
        int beg = rowptr[d], end = rowptr[d + 1];
        int EC = end - beg;
        float a0 = 0.f, a1 = 0.f;
        int j = 0;
        for (; j + 7 < EC; j += 8) {           // 8 edges: 4 indep 256B wave-gathers
            int s0 = e_src[beg + j + 0 + half];
            int s1 = e_src[beg + j + 2 + half];
            int s2 = e_src[beg + j + 4 + half];
            int s3 = e_src[beg + j + 6 + half];
            ushort2 u0 = xw[(size_t)s0 * 32 + cp];
            ushort2 u1 = xw[(size_t)s1 * 32 + cp];
            ushort2 u2 = xw[(size_t)s2 * 32 + cp];
            ushort2 u3 = xw[(size_t)s3 * 32 + cp];
            a0 += bf2f(u0.x) + bf2f(u1.x) + bf2f(u2.x) + bf2f(u3.x);
            a1 += bf2f(u0.y) + bf2f(u1.y) + bf2f(u2.y) + bf2f(u3.y);
        }
        for (; j + 1 < EC; j += 2) {           // leftover pairs (<=3)
            int s = e_src[beg + j + half];
            ushort2 u = xw[(size_t)s * 32 + cp];
            a0 += bf2f(u.x);
            a1 += bf2f(u.y);
        }
        // tail: possibly one leftover edge, plus the self-loop row
        bool active = true;
        int s_t;
        if (j < EC) { s_t = half ? d : e_src[beg + j]; }   // half0 = last edge, half1 = self
        else        { s_t = d; active = (half == 0); }     // self only
        if (active) {
            ushort2 u = xw[(size_t)s_t * 32 + cp];
            a0 += bf2f(u.x);
            a1 += bf2f(u.y);
        }
        a0 += __shfl_xor(a0, 32);
        a1 += __shfl_xor(a1, 32);
        float dv = dinv[d];
        float h0 = a0 * dv + bb0;
        float hv1 = a1 * dv + bb1;
        if (half == 0) {
            ((float2*)(h1 + (size_t)d * HID))[cp] = make_float2(h0, hv1);
            ssum0 += h0; ssq0 += h0 * h0;
            ssum1 += hv1; ssq1 += hv1 * hv1;
        }
    }
    if (half == 0) {
        lsum[wave][2 * cp] = ssum0; lsum[wave][2 * cp + 1] = ssum1;
        lsq[wave][2 * cp] = ssq0;   lsq[wave][2 * cp + 1] = ssq1;
    }
    __syncthreads();
    if (wave == 0) {
        float ts = lsum[0][lane] + lsum[1][lane] + lsum[2][lane] + lsum[3][lane];
        float tq = lsq[0][lane] + lsq[1][lane] + lsq[2][lane] + lsq[3][lane];
        atomicAdd(&sums1[lane], ts);
        atomicAdd(&sums1[64 + lane], tq);
    }
}

// ---------------- gemm2: xw2' = dinv .* (relu(BN1(h1)) @ W2) ----------------
__global__ __launch_bounds__(256) void gemm2_kernel(const float* __restrict__ h1,
                                                    const float* __restrict__ sums1,
                                                    const float* __restrict__ g1,
                                                    const float* __restrict__ be1,
                                                    const float* __restrict__ W2,
                                                    const float* __restrict__ dinv,
                                                    float* __restrict__ xw2) {
    int lane = threadIdx.x & 63;
    int row = blockIdx.x * 4 + (threadIdx.x >> 6);
    if (row >= NN) return;
    int c = lane;
    const float invn = 1.0f / (float)NN;
    float mu = sums1[c] * invn;
    float var = sums1[64 + c] * invn - mu * mu;
    float sc = g1[c] * rsqrtf(var + EPSV);
    float sh = be1[c] - mu * sc;
    float h = h1[(size_t)row * HID + c] * sc + sh;
    h = fmaxf(h, 0.f);
    float p0 = h * W2[c * 2 + 0];
    float p1 = h * W2[c * 2 + 1];
    for (int o = 32; o; o >>= 1) {
        p0 += __shfl_xor(p0, o);
        p1 += __shfl_xor(p1, o);
    }
    if (lane == 0) {
        float dv = dinv[row];
        xw2[(size_t)row * 2 + 0] = p0 * dv;
        xw2[(size_t)row * 2 + 1] = p1 * dv;
    }
}

// ---------------- agg2: z2 = dinv_d*(sum xw2'[s] + xw2'[d]) + b2, fused BN2 stats ----------------
__global__ __launch_bounds__(256) void agg2_kernel(const float* __restrict__ xw2,
                                                   const int* __restrict__ rowptr,
                                                   const int* __restrict__ e_src,
                                                   const float* __restrict__ dinv,
                                                   const float* __restrict__ b2,
                                                   float* __restrict__ z2,
                                                   float* __restrict__ sums2) {
    int d = blockIdx.x * 256 + threadIdx.x;
    float z0 = 0.f, z1 = 0.f;
    if (d < NN) {
        int beg = rowptr[d], end = rowptr[d + 1];
        float a0 = 0.f, a1 = 0.f;
        for (int e = beg; e < end; e++) {
            int s = e_src[e];
            a0 += xw2[(size_t)s * 2 + 0];
            a1 += xw2[(size_t)s * 2 + 1];
        }
        a0 += xw2[(size_t)d * 2 + 0];
        a1 += xw2[(size_t)d * 2 + 1];
        float dv = dinv[d];
        z0 = a0 * dv + b2[0];
        z1 = a1 * dv + b2[1];
        z2[(size_t)d * 2 + 0] = z0;
        z2[(size_t)d * 2 + 1] = z1;
    }
    float s0 = z0, s1 = z1, q0 = z0 * z0, q1 = z1 * z1;
    for (int o = 32; o; o >>= 1) {
        s0 += __shfl_xor(s0, o);
        s1 += __shfl_xor(s1, o);
        q0 += __shfl_xor(q0, o);
        q1 += __shfl_xor(q1, o);
    }
    if ((threadIdx.x & 63) == 0) {
        atomicAdd(&sums2[0], s0);
        atomicAdd(&sums2[1], s1);
        atomicAdd(&sums2[2], q0);
        atomicAdd(&sums2[3], q1);
    }
}

// ---------------- decoder: out = BN2(z2) @ Wd + bd  (BN2 finalize folded in) ----------------
__global__ __launch_bounds__(256) void decoder_kernel(const float* __restrict__ z2,
                                                      const float* __restrict__ sums2,
                                                      const float* __restrict__ g2,
                                                      const float* __restrict__ be2,
                                                      const float* __restrict__ Wd,
                                                      const float* __restrict__ bd,
                                                      float* __restrict__ out) {
    int g = blockIdx.x * 256 + threadIdx.x;
    int row = g >> 6;
    int c4 = (g & 63) * 4;
    const float invn = 1.0f / (float)NN;
    float mu0 = sums2[0] * invn, mu1 = sums2[1] * invn;
    float v0 = sums2[2] * invn - mu0 * mu0;
    float v1 = sums2[3] * invn - mu1 * mu1;
    float sc0 = g2[0] * rsqrtf(v0 + EPSV), sh0 = be2[0] - mu0 * sc0;
    float sc1 = g2[1] * rsqrtf(v1 + EPSV), sh1 = be2[1] - mu1 * sc1;
    float zb0 = z2[(size_t)row * 2 + 0] * sc0 + sh0;
    float zb1 = z2[(size_t)row * 2 + 1] * sc1 + sh1;
    float4 w0 = *(const float4*)(Wd + c4);
    float4 w1 = *(const float4*)(Wd + INC + c4);
    float4 bb = *(const float4*)(bd + c4);
    float4 o;
    o.x = zb0 * w0.x + zb1 * w1.x + bb.x;
    o.y = zb0 * w0.y + zb1 * w1.y + bb.y;
    o.z = zb0 * w0.z + zb1 * w1.z + bb.z;
    o.w = zb0 * w0.w + zb1 * w1.w + bb.w;
    *(float4*)(out + (size_t)row * INC + c4) = o;
}

// ---------------- launch ----------------
static inline size_t align256(size_t x) { return (x + 255) & ~(size_t)255; }

extern "C" void kernel_launch(void* const* d_in, const int* in_sizes, int n_in,
                              void* d_out, int out_size, void* d_ws, size_t ws_size,
                              hipStream_t stream) {
    const float* x  = (const float*)d_in[0];
    const int*   ei = (const int*)d_in[1];     // [2, E] int32
    const float* W1 = (const float*)d_in[2];
    const float* b1 = (const float*)d_in[3];
    const float* g1 = (const float*)d_in[4];
    const float* be1 = (const float*)d_in[5];
    const float* W2 = (const float*)d_in[6];
    const float* b2 = (const float*)d_in[7];
    const float* g2 = (const float*)d_in[8];
    const float* be2 = (const float*)d_in[9];
    const float* Wd = (const float*)d_in[10];
    const float* bd = (const float*)d_in[11];
    float* out = (float*)d_out;

    const int* src = ei;
    const int* dst = ei + NE;

    char* ws = (char*)d_ws;
    size_t off = 0;
    int* cnt = (int*)(ws + off);        off = align256(off + NN * 4);
    int* fill = (int*)(ws + off);       off = align256(off + NN * 4);
    float* sums1 = (float*)(ws + off);  off = align256(off + 128 * 4);
    float* sums2 = (float*)(ws + off);  off = align256(off + 4 * 4);
    size_t zero_bytes = off;
    int* rowptr = (int*)(ws + off);     off = align256(off + (NN + 1) * 4);
    float* dinv = (float*)(ws + off);   off = align256(off + NN * 4);
    int* btot = (int*)(ws + off);       off = align256(off + NBLK * 4);
    int* boff = (int*)(ws + off);       off = align256(off + NBLK * 4);
    int* e_src = (int*)(ws + off);      off = align256(off + (size_t)NE * 4 + 64);
    unsigned short* xw1b = (unsigned short*)(ws + off); off = align256(off + (size_t)NN * HID * 2);
    float* h1 = (float*)(ws + off);     off = align256(off + (size_t)NN * HID * 4);
    float* xw2 = (float*)(ws + off);    off = align256(off + (size_t)NN * 2 * 4);
    float* z2 = (float*)(ws + off);     off = align256(off + (size_t)NN * 2 * 4);
    (void)ws_size; (void)in_sizes; (void)n_in; (void)out_size;

    hipMemsetAsync(d_ws, 0, zero_bytes, stream);

    hist_kernel<<<2048, 256, 0, stream>>>(dst, cnt);
    scan_btot_kernel<<<NBLK, 256, 0, stream>>>(cnt, btot);
    scan_boff_kernel<<<1, 128, 0, stream>>>(btot, boff);
    scan_rowptr_kernel<<<NBLK, 256, 0, stream>>>(cnt, boff, rowptr, dinv);
    scatter_kernel<<<2048, 256, 0, stream>>>(src, dst, rowptr, fill, e_src);
    gemm1_kernel<<<NN / G1_ROWS, 256, 0, stream>>>(x, W1, dinv, xw1b);
    agg1_kernel<<<2048, 256, 0, stream>>>(xw1b, rowptr, e_src, dinv, b1, h1, sums1);
    gemm2_kernel<<<(NN + 3) / 4, 256, 0, stream>>>(h1, sums1, g1, be1, W2, dinv, xw2);
    agg2_kernel<<<(NN + 255) / 256, 256, 0, stream>>>(xw2, rowptr, e_src, dinv, b2, z2, sums2);
    decoder_kernel<<<(NN * HID) / 256, 256, 0, stream>>>(z2, sums2, g2, be2, Wd, bd, out);
}

// Round 5
// 460.670 us; speedup vs baseline: 2.0716x; 1.3342x over previous
//
#include <hip/hip_runtime.h>
#include <hip/hip_bf16.h>

#define NN 100000
#define NE 3200000
#define INC 256
#define HID 64
#define OUTC 2
#define EPSV 1e-5f

#define SCAN_CHUNK 1024
#define NBLK ((NN + SCAN_CHUNK - 1) / SCAN_CHUNK)   // 98

#define NBUCK 128
#define BCAP  26000          // mean 25000, sigma ~157 -> +6.4 sigma margin
#define BIN_CHUNK 4096
#define BIN_K 16             // edges per thread (256 threads * 16 = 4096)
#define BIN_GRID ((NE + BIN_CHUNK - 1) / BIN_CHUNK)  // 782

static __device__ __forceinline__ float bf2f(unsigned short u) {
    return __uint_as_float((unsigned)u << 16);
}

// ---------------- bin: partition edges into 128 dst-range buckets ----------------
// Per block: 4096 edges in registers; LDS bucket histogram + slot assignment;
// one global atomicAdd per (block,bucket) reserves a contiguous region; packed
// int2(src,dst) writes in ~256B chunks -> no partial-line write amplification.
__global__ __launch_bounds__(256) void bin_kernel(const int* __restrict__ src,
                                                  const int* __restrict__ dst,
                                                  int* __restrict__ gtail,
                                                  int2* __restrict__ bbuf) {
    __shared__ int bcnt[NBUCK], bbase[NBUCK];
    int t = threadIdx.x;
    if (t < NBUCK) bcnt[t] = 0;
    __syncthreads();
    int base = blockIdx.x * BIN_CHUNK;
    int s[BIN_K], d[BIN_K], sl[BIN_K], bk[BIN_K];
#pragma unroll
    for (int r = 0; r < BIN_K; r++) {
        int i = base + r * 256 + t;
        bool v = i < NE;
        s[r] = v ? src[i] : 0;
        d[r] = v ? dst[i] : 0;
        bk[r] = (int)(((unsigned)d[r] * (unsigned)NBUCK) / (unsigned)NN);
        sl[r] = v ? atomicAdd(&bcnt[bk[r]], 1) : 0;
    }
    __syncthreads();
    if (t < NBUCK) bbase[t] = bcnt[t] ? atomicAdd(&gtail[t], bcnt[t]) : 0;
    __syncthreads();
#pragma unroll
    for (int r = 0; r < BIN_K; r++) {
        int i = base + r * 256 + t;
        if (i < NE) {
            int b = bk[r];
            bbuf[(size_t)b * BCAP + bbase[b] + sl[r]] = make_int2(s[r], d[r]);
        }
    }
}

// ---------------- hist2: per-bucket LDS node histogram -> cnt (no atomics to HBM) ----------------
__global__ __launch_bounds__(256) void hist2_kernel(const int2* __restrict__ bbuf,
                                                    const int* __restrict__ gtail,
                                                    int* __restrict__ cnt) {
    __shared__ int h[800];
    int b = blockIdx.x, t = threadIdx.x;
    int nb = (b * NN + NBUCK - 1) >> 7;
    int ne_ = ((b + 1) * NN + NBUCK - 1) >> 7;
    int range = ne_ - nb;
    for (int i = t; i < range; i += 256) h[i] = 0;
    __syncthreads();
    int ecnt = gtail[b];
    const int2* p = bbuf + (size_t)b * BCAP;
    for (int i = t; i < ecnt; i += 256) {
        int2 e = p[i];
        atomicAdd(&h[e.y - nb], 1);
    }
    __syncthreads();
    for (int i = t; i < range; i += 256) cnt[nb + i] = h[i];
}

// ---------------- scan step 1: per-chunk totals ----------------
__global__ void scan_btot_kernel(const int* __restrict__ cnt, int* __restrict__ btot) {
    __shared__ int red[4];
    int b = blockIdx.x, t = threadIdx.x;
    int base = b * SCAN_CHUNK;
    int v = 0;
    for (int j = t; j < SCAN_CHUNK; j += 256) {
        int idx = base + j;
        v += (idx < NN) ? cnt[idx] : 0;
    }
    for (int o = 32; o; o >>= 1) v += __shfl_xor(v, o);
    int wave = t >> 6, lane = t & 63;
    if (lane == 0) red[wave] = v;
    __syncthreads();
    if (t == 0) btot[b] = red[0] + red[1] + red[2] + red[3];
}

// ---------------- scan step 2: exclusive scan of chunk totals ----------------
__global__ void scan_boff_kernel(const int* __restrict__ btot, int* __restrict__ boff) {
    __shared__ int wtot[2];
    int t = threadIdx.x;           // 128 threads
    int lane = t & 63, wave = t >> 6;
    int v = (t < NBLK) ? btot[t] : 0;
    int s = v;
    for (int o = 1; o < 64; o <<= 1) {
        int u = __shfl_up(s, o);
        if (lane >= o) s += u;
    }
    if (lane == 63) wtot[wave] = s;
    __syncthreads();
    int add = (wave == 1) ? wtot[0] : 0;
    if (t < NBLK) boff[t] = s - v + add;   // exclusive prefix
}

// ---------------- scan step 3: full rowptr + dinv ----------------
__global__ void scan_rowptr_kernel(const int* __restrict__ cnt, const int* __restrict__ boff,
                                   int* __restrict__ rowptr, float* __restrict__ dinv) {
    __shared__ int wsum[4];
    int b = blockIdx.x, t = threadIdx.x;
    int lane = t & 63, wave = t >> 6;
    int idx = b * SCAN_CHUNK + t * 4;
    int c0 = (idx + 0 < NN) ? cnt[idx + 0] : 0;
    int c1 = (idx + 1 < NN) ? cnt[idx + 1] : 0;
    int c2 = (idx + 2 < NN) ? cnt[idx + 2] : 0;
    int c3 = (idx + 3 < NN) ? cnt[idx + 3] : 0;
    int local = c0 + c1 + c2 + c3;
    int s = local;
    for (int o = 1; o < 64; o <<= 1) {
        int u = __shfl_up(s, o);
        if (lane >= o) s += u;
    }
    if (lane == 63) wsum[wave] = s;
    __syncthreads();
    if (t == 0) {
        int run = 0;
        for (int w = 0; w < 4; w++) { int x = wsum[w]; wsum[w] = run; run += x; }
    }
    __syncthreads();
    int start = boff[b] + wsum[wave] + (s - local);
    if (idx + 0 < NN) { rowptr[idx + 0] = start;                dinv[idx + 0] = rsqrtf((float)(c0 + 1)); }
    if (idx + 1 < NN) { rowptr[idx + 1] = start + c0;           dinv[idx + 1] = rsqrtf((float)(c1 + 1)); }
    if (idx + 2 < NN) { rowptr[idx + 2] = start + c0 + c1;      dinv[idx + 2] = rsqrtf((float)(c2 + 1)); }
    if (idx + 3 < NN) { rowptr[idx + 3] = start + c0 + c1 + c2; dinv[idx + 3] = rsqrtf((float)(c3 + 1)); }
    if (b == 0 && t == 0) rowptr[NN] = NE;
}

// ---------------- scatter2: per-bucket CSR fill; LDS fill counters; L2-resident e_src window ----------------
__global__ __launch_bounds__(256) void scatter2_kernel(const int2* __restrict__ bbuf,
                                                       const int* __restrict__ gtail,
                                                       const int* __restrict__ rowptr,
                                                       int* __restrict__ e_src) {
    __shared__ int fill[800];
    int b = blockIdx.x, t = threadIdx.x;
    int nb = (b * NN + NBUCK - 1) >> 7;
    int ne_ = ((b + 1) * NN + NBUCK - 1) >> 7;
    int range = ne_ - nb;
    for (int i = t; i < range; i += 256) fill[i] = 0;
    __syncthreads();
    int ecnt = gtail[b];
    const int2* p = bbuf + (size_t)b * BCAP;
    for (int i = t; i < ecnt; i += 256) {
        int2 e = p[i];
        int pos = rowptr[e.y] + atomicAdd(&fill[e.y - nb], 1);
        e_src[pos] = e.x;
    }
}

// ---------------- GEMM1: xw1b = bf16( dinv .* (x @ W1) )  ([N,256]@[256,64]) ----------------
#define G1_ROWS 32
__global__ __launch_bounds__(256) void gemm1_kernel(const float* __restrict__ x,
                                                    const float* __restrict__ W1,
                                                    const float* __restrict__ dinv,
                                                    unsigned short* __restrict__ xw1b) {
    __shared__ float xt[G1_ROWS][INC];   // 32 KB
    int t = threadIdx.x;
    size_t base = (size_t)blockIdx.x * G1_ROWS;
    const float4* xg = (const float4*)(x + base * INC);
    float4* xs = (float4*)xt;
#pragma unroll
    for (int i = 0; i < (G1_ROWS * INC / 4) / 256; i++)
        xs[t + i * 256] = xg[t + i * 256];
    __syncthreads();
    int lane = t & 63;
    int wave = t >> 6;
    int r0 = wave * 8;                    // 8 rows per wave
    float acc[8] = {0.f, 0.f, 0.f, 0.f, 0.f, 0.f, 0.f, 0.f};
    const float* wp = W1 + lane;
#pragma unroll 4
    for (int k = 0; k < INC; k += 2) {
        float w0 = wp[k * HID];
        float w1 = wp[(k + 1) * HID];
#pragma unroll
        for (int r = 0; r < 8; r++) {
            float2 xv = *(const float2*)&xt[r0 + r][k];
            acc[r] += xv.x * w0 + xv.y * w1;
        }
    }
#pragma unroll
    for (int r = 0; r < 8; r++) {
        float v = acc[r] * dinv[base + r0 + r];
        __hip_bfloat16 hb = __float2bfloat16(v);   // RNE
        xw1b[(base + r0 + r) * HID + lane] = *(unsigned short*)&hb;
    }
}

// ---------------- agg1: h1 = dinv_d*(sum_edges xw1'[s] + xw1'[d]) + b1, fused BN1 stats ----------------
__global__ __launch_bounds__(256) void agg1_kernel(const unsigned short* __restrict__ xw1b,
                                                   const int* __restrict__ rowptr,
                                                   const int* __restrict__ e_src,
                                                   const float* __restrict__ dinv,
                                                   const float* __restrict__ b1,
                                                   float* __restrict__ h1,
                                                   float* __restrict__ sums1) {
    __shared__ float lsum[4][64], lsq[4][64];
    int lane = threadIdx.x & 63;
    int wave = threadIdx.x >> 6;
    int half = lane >> 5;
    int cp = lane & 31;                     // channel pair: channels 2cp, 2cp+1
    int wid = blockIdx.x * 4 + wave;
    int wstride = gridDim.x * 4;
    float bb0 = b1[2 * cp], bb1 = b1[2 * cp + 1];
    float ssum0 = 0.f, ssq0 = 0.f, ssum1 = 0.f, ssq1 = 0.f;
    const ushort2* xw = (const ushort2*)xw1b;   // row = 32 ushort2
    for (int d0 = wid; d0 < NN; d0 += wstride) {
        int d = __builtin_amdgcn_readfirstlane(d0);
        int beg = rowptr[d], end = rowptr[d + 1];
        int EC = end - beg;
        float a0 = 0.f, a1 = 0.f;
        int j = 0;
        for (; j + 7 < EC; j += 8) {           // 8 edges: 4 indep 256B wave-gathers
            int s0 = e_src[beg + j + 0 + half];
            int s1 = e_src[beg + j + 2 + half];
            int s2 = e_src[beg + j + 4 + half];
            int s3 = e_src[beg + j + 6 + half];
            ushort2 u0 = xw[(size_t)s0 * 32 + cp];
            ushort2 u1 = xw[(size_t)s1 * 32 + cp];
            ushort2 u2 = xw[(size_t)s2 * 32 + cp];
            ushort2 u3 = xw[(size_t)s3 * 32 + cp];
            a0 += bf2f(u0.x) + bf2f(u1.x) + bf2f(u2.x) + bf2f(u3.x);
            a1 += bf2f(u0.y) + bf2f(u1.y) + bf2f(u2.y) + bf2f(u3.y);
        }
        for (; j + 1 < EC; j += 2) {           // leftover pairs (<=3)
            int s = e_src[beg + j + half];
            ushort2 u = xw[(size_t)s * 32 + cp];
            a0 += bf2f(u.x);
            a1 += bf2f(u.y);
        }
        // tail: possibly one leftover edge, plus the self-loop row
        bool active = true;
        int s_t;
        if (j < EC) { s_t = half ? d : e_src[beg + j]; }   // half0 = last edge, half1 = self
        else        { s_t = d; active = (half == 0); }     // self only
        if (active) {
            ushort2 u = xw[(size_t)s_t * 32 + cp];
            a0 += bf2f(u.x);
            a1 += bf2f(u.y);
        }
        a0 += __shfl_xor(a0, 32);
        a1 += __shfl_xor(a1, 32);
        float dv = dinv[d];
        float h0 = a0 * dv + bb0;
        float hv1 = a1 * dv + bb1;
        if (half == 0) {
            ((float2*)(h1 + (size_t)d * HID))[cp] = make_float2(h0, hv1);
            ssum0 += h0; ssq0 += h0 * h0;
            ssum1 += hv1; ssq1 += hv1 * hv1;
        }
    }
    if (half == 0) {
        lsum[wave][2 * cp] = ssum0; lsum[wave][2 * cp + 1] = ssum1;
        lsq[wave][2 * cp] = ssq0;   lsq[wave][2 * cp + 1] = ssq1;
    }
    __syncthreads();
    if (wave == 0) {
        float ts = lsum[0][lane] + lsum[1][lane] + lsum[2][lane] + lsum[3][lane];
        float tq = lsq[0][lane] + lsq[1][lane] + lsq[2][lane] + lsq[3][lane];
        atomicAdd(&sums1[lane], ts);
        atomicAdd(&sums1[64 + lane], tq);
    }
}

// ---------------- gemm2: xw2' = dinv .* (relu(BN1(h1)) @ W2) ----------------
__global__ __launch_bounds__(256) void gemm2_kernel(const float* __restrict__ h1,
                                                    const float* __restrict__ sums1,
                                                    const float* __restrict__ g1,
                                                    const float* __restrict__ be1,
                                                    const float* __restrict__ W2,
                                                    const float* __restrict__ dinv,
                                                    float* __restrict__ xw2) {
    int lane = threadIdx.x & 63;
    int row = blockIdx.x * 4 + (threadIdx.x >> 6);
    if (row >= NN) return;
    int c = lane;
    const float invn = 1.0f / (float)NN;
    float mu = sums1[c] * invn;
    float var = sums1[64 + c] * invn - mu * mu;
    float sc = g1[c] * rsqrtf(var + EPSV);
    float sh = be1[c] - mu * sc;
    float h = h1[(size_t)row * HID + c] * sc + sh;
    h = fmaxf(h, 0.f);
    float p0 = h * W2[c * 2 + 0];
    float p1 = h * W2[c * 2 + 1];
    for (int o = 32; o; o >>= 1) {
        p0 += __shfl_xor(p0, o);
        p1 += __shfl_xor(p1, o);
    }
    if (lane == 0) {
        float dv = dinv[row];
        xw2[(size_t)row * 2 + 0] = p0 * dv;
        xw2[(size_t)row * 2 + 1] = p1 * dv;
    }
}

// ---------------- agg2: z2 = dinv_d*(sum xw2'[s] + xw2'[d]) + b2, fused BN2 stats ----------------
__global__ __launch_bounds__(256) void agg2_kernel(const float* __restrict__ xw2,
                                                   const int* __restrict__ rowptr,
                                                   const int* __restrict__ e_src,
                                                   const float* __restrict__ dinv,
                                                   const float* __restrict__ b2,
                                                   float* __restrict__ z2,
                                                   float* __restrict__ sums2) {
    int d = blockIdx.x * 256 + threadIdx.x;
    float z0 = 0.f, z1 = 0.f;
    if (d < NN) {
        int beg = rowptr[d], end = rowptr[d + 1];
        float a0 = 0.f, a1 = 0.f;
        for (int e = beg; e < end; e++) {
            int s = e_src[e];
            a0 += xw2[(size_t)s * 2 + 0];
            a1 += xw2[(size_t)s * 2 + 1];
        }
        a0 += xw2[(size_t)d * 2 + 0];
        a1 += xw2[(size_t)d * 2 + 1];
        float dv = dinv[d];
        z0 = a0 * dv + b2[0];
        z1 = a1 * dv + b2[1];
        z2[(size_t)d * 2 + 0] = z0;
        z2[(size_t)d * 2 + 1] = z1;
    }
    float s0 = z0, s1 = z1, q0 = z0 * z0, q1 = z1 * z1;
    for (int o = 32; o; o >>= 1) {
        s0 += __shfl_xor(s0, o);
        s1 += __shfl_xor(s1, o);
        q0 += __shfl_xor(q0, o);
        q1 += __shfl_xor(q1, o);
    }
    if ((threadIdx.x & 63) == 0) {
        atomicAdd(&sums2[0], s0);
        atomicAdd(&sums2[1], s1);
        atomicAdd(&sums2[2], q0);
        atomicAdd(&sums2[3], q1);
    }
}

// ---------------- decoder: out = BN2(z2) @ Wd + bd  (BN2 finalize folded in) ----------------
__global__ __launch_bounds__(256) void decoder_kernel(const float* __restrict__ z2,
                                                      const float* __restrict__ sums2,
                                                      const float* __restrict__ g2,
                                                      const float* __restrict__ be2,
                                                      const float* __restrict__ Wd,
                                                      const float* __restrict__ bd,
                                                      float* __restrict__ out) {
    int g = blockIdx.x * 256 + threadIdx.x;
    int row = g >> 6;
    int c4 = (g & 63) * 4;
    const float invn = 1.0f / (float)NN;
    float mu0 = sums2[0] * invn, mu1 = sums2[1] * invn;
    float v0 = sums2[2] * invn - mu0 * mu0;
    float v1 = sums2[3] * invn - mu1 * mu1;
    float sc0 = g2[0] * rsqrtf(v0 + EPSV), sh0 = be2[0] - mu0 * sc0;
    float sc1 = g2[1] * rsqrtf(v1 + EPSV), sh1 = be2[1] - mu1 * sc1;
    float zb0 = z2[(size_t)row * 2 + 0] * sc0 + sh0;
    float zb1 = z2[(size_t)row * 2 + 1] * sc1 + sh1;
    float4 w0 = *(const float4*)(Wd + c4);
    float4 w1 = *(const float4*)(Wd + INC + c4);
    float4 bb = *(const float4*)(bd + c4);
    float4 o;
    o.x = zb0 * w0.x + zb1 * w1.x + bb.x;
    o.y = zb0 * w0.y + zb1 * w1.y + bb.y;
    o.z = zb0 * w0.z + zb1 * w1.z + bb.z;
    o.w = zb0 * w0.w + zb1 * w1.w + bb.w;
    *(float4*)(out + (size_t)row * INC + c4) = o;
}

// ---------------- launch ----------------
static inline size_t align256(size_t x) { return (x + 255) & ~(size_t)255; }

extern "C" void kernel_launch(void* const* d_in, const int* in_sizes, int n_in,
                              void* d_out, int out_size, void* d_ws, size_t ws_size,
                              hipStream_t stream) {
    const float* x  = (const float*)d_in[0];
    const int*   ei = (const int*)d_in[1];     // [2, E] int32
    const float* W1 = (const float*)d_in[2];
    const float* b1 = (const float*)d_in[3];
    const float* g1 = (const float*)d_in[4];
    const float* be1 = (const float*)d_in[5];
    const float* W2 = (const float*)d_in[6];
    const float* b2 = (const float*)d_in[7];
    const float* g2 = (const float*)d_in[8];
    const float* be2 = (const float*)d_in[9];
    const float* Wd = (const float*)d_in[10];
    const float* bd = (const float*)d_in[11];
    float* out = (float*)d_out;

    const int* src = ei;
    const int* dst = ei + NE;

    char* ws = (char*)d_ws;
    size_t off = 0;
    int* gtail = (int*)(ws + off);      off = align256(off + NBUCK * 4);
    float* sums1 = (float*)(ws + off);  off = align256(off + 128 * 4);
    float* sums2 = (float*)(ws + off);  off = align256(off + 4 * 4);
    size_t zero_bytes = off;
    int* cnt = (int*)(ws + off);        off = align256(off + NN * 4);
    int* rowptr = (int*)(ws + off);     off = align256(off + (NN + 1) * 4);
    float* dinv = (float*)(ws + off);   off = align256(off + NN * 4);
    int* btot = (int*)(ws + off);       off = align256(off + NBLK * 4);
    int* boff = (int*)(ws + off);       off = align256(off + NBLK * 4);
    int2* bbuf = (int2*)(ws + off);     off = align256(off + (size_t)NBUCK * BCAP * 8);
    int* e_src = (int*)(ws + off);      off = align256(off + (size_t)NE * 4 + 64);
    unsigned short* xw1b = (unsigned short*)(ws + off); off = align256(off + (size_t)NN * HID * 2);
    float* h1 = (float*)(ws + off);     off = align256(off + (size_t)NN * HID * 4);
    float* xw2 = (float*)(ws + off);    off = align256(off + (size_t)NN * 2 * 4);
    float* z2 = (float*)(ws + off);     off = align256(off + (size_t)NN * 2 * 4);
    (void)ws_size; (void)in_sizes; (void)n_in; (void)out_size;

    hipMemsetAsync(d_ws, 0, zero_bytes, stream);

    bin_kernel<<<BIN_GRID, 256, 0, stream>>>(src, dst, gtail, bbuf);
    hist2_kernel<<<NBUCK, 256, 0, stream>>>(bbuf, gtail, cnt);
    scan_btot_kernel<<<NBLK, 256, 0, stream>>>(cnt, btot);
    scan_boff_kernel<<<1, 128, 0, stream>>>(btot, boff);
    scan_rowptr_kernel<<<NBLK, 256, 0, stream>>>(cnt, boff, rowptr, dinv);
    scatter2_kernel<<<NBUCK, 256, 0, stream>>>(bbuf, gtail, rowptr, e_src);
    gemm1_kernel<<<NN / G1_ROWS, 256, 0, stream>>>(x, W1, dinv, xw1b);
    agg1_kernel<<<2048, 256, 0, stream>>>(xw1b, rowptr, e_src, dinv, b1, h1, sums1);
    gemm2_kernel<<<(NN + 3) / 4, 256, 0, stream>>>(h1, sums1, g1, be1, W2, dinv, xw2);
    agg2_kernel<<<(NN + 255) / 256, 256, 0, stream>>>(xw2, rowptr, e_src, dinv, b2, z2, sums2);
    decoder_kernel<<<(NN * HID) / 256, 256, 0, stream>>>(z2, sums2, g2, be2, Wd, bd, out);
}

// Round 6
// 402.364 us; speedup vs baseline: 2.3718x; 1.1449x over previous
//
#include <hip/hip_runtime.h>
#include <hip/hip_bf16.h>

#define NN 100000
#define NE 3200000
#define INC 256
#define HID 64
#define OUTC 2
#define EPSV 1e-5f

#define SCAN_CHUNK 1024
#define NBLK ((NN + SCAN_CHUNK - 1) / SCAN_CHUNK)   // 98

#define NBUCK 128
#define BCAP  26000          // mean 25000, sigma ~157 -> +6.4 sigma margin
#define BIN_CHUNK 4096
#define BIN_K 16             // edges per thread (256 threads * 16 = 4096)
#define BIN_GRID ((NE + BIN_CHUNK - 1) / BIN_CHUNK)  // 782

typedef short short8 __attribute__((ext_vector_type(8)));
typedef float f32x4 __attribute__((ext_vector_type(4)));

static __device__ __forceinline__ float bf2f(unsigned short u) {
    return __uint_as_float((unsigned)u << 16);
}
static __device__ __forceinline__ unsigned short f2bf(float f) {
    __hip_bfloat16 hb = __float2bfloat16(f);   // RNE
    return *(unsigned short*)&hb;
}

// ---------------- bin: partition edges into 128 dst-range buckets ----------------
__global__ __launch_bounds__(256) void bin_kernel(const int* __restrict__ src,
                                                  const int* __restrict__ dst,
                                                  int* __restrict__ gtail,
                                                  int2* __restrict__ bbuf) {
    __shared__ int bcnt[NBUCK], bbase[NBUCK];
    int t = threadIdx.x;
    if (t < NBUCK) bcnt[t] = 0;
    __syncthreads();
    int base = blockIdx.x * BIN_CHUNK;
    int s[BIN_K], d[BIN_K], sl[BIN_K], bk[BIN_K];
#pragma unroll
    for (int r = 0; r < BIN_K; r++) {
        int i = base + r * 256 + t;
        bool v = i < NE;
        s[r] = v ? src[i] : 0;
        d[r] = v ? dst[i] : 0;
        bk[r] = (int)(((unsigned)d[r] * (unsigned)NBUCK) / (unsigned)NN);
        sl[r] = v ? atomicAdd(&bcnt[bk[r]], 1) : 0;
    }
    __syncthreads();
    if (t < NBUCK) bbase[t] = bcnt[t] ? atomicAdd(&gtail[t], bcnt[t]) : 0;
    __syncthreads();
#pragma unroll
    for (int r = 0; r < BIN_K; r++) {
        int i = base + r * 256 + t;
        if (i < NE) {
            int b = bk[r];
            bbuf[(size_t)b * BCAP + bbase[b] + sl[r]] = make_int2(s[r], d[r]);
        }
    }
}

// ---------------- hist2: per-bucket LDS node histogram -> cnt ----------------
__global__ __launch_bounds__(256) void hist2_kernel(const int2* __restrict__ bbuf,
                                                    const int* __restrict__ gtail,
                                                    int* __restrict__ cnt) {
    __shared__ int h[800];
    int b = blockIdx.x, t = threadIdx.x;
    int nb = (b * NN + NBUCK - 1) >> 7;
    int ne_ = ((b + 1) * NN + NBUCK - 1) >> 7;
    int range = ne_ - nb;
    for (int i = t; i < range; i += 256) h[i] = 0;
    __syncthreads();
    int ecnt = gtail[b];
    const int2* p = bbuf + (size_t)b * BCAP;
    for (int i = t; i < ecnt; i += 256) {
        int2 e = p[i];
        atomicAdd(&h[e.y - nb], 1);
    }
    __syncthreads();
    for (int i = t; i < range; i += 256) cnt[nb + i] = h[i];
}

// ---------------- scan step 1: per-chunk totals ----------------
__global__ void scan_btot_kernel(const int* __restrict__ cnt, int* __restrict__ btot) {
    __shared__ int red[4];
    int b = blockIdx.x, t = threadIdx.x;
    int base = b * SCAN_CHUNK;
    int v = 0;
    for (int j = t; j < SCAN_CHUNK; j += 256) {
        int idx = base + j;
        v += (idx < NN) ? cnt[idx] : 0;
    }
    for (int o = 32; o; o >>= 1) v += __shfl_xor(v, o);
    int wave = t >> 6, lane = t & 63;
    if (lane == 0) red[wave] = v;
    __syncthreads();
    if (t == 0) btot[b] = red[0] + red[1] + red[2] + red[3];
}

// ---------------- scan step 2: exclusive scan of chunk totals ----------------
__global__ void scan_boff_kernel(const int* __restrict__ btot, int* __restrict__ boff) {
    __shared__ int wtot[2];
    int t = threadIdx.x;           // 128 threads
    int lane = t & 63, wave = t >> 6;
    int v = (t < NBLK) ? btot[t] : 0;
    int s = v;
    for (int o = 1; o < 64; o <<= 1) {
        int u = __shfl_up(s, o);
        if (lane >= o) s += u;
    }
    if (lane == 63) wtot[wave] = s;
    __syncthreads();
    int add = (wave == 1) ? wtot[0] : 0;
    if (t < NBLK) boff[t] = s - v + add;   // exclusive prefix
}

// ---------------- scan step 3: full rowptr + dinv ----------------
__global__ void scan_rowptr_kernel(const int* __restrict__ cnt, const int* __restrict__ boff,
                                   int* __restrict__ rowptr, float* __restrict__ dinv) {
    __shared__ int wsum[4];
    int b = blockIdx.x, t = threadIdx.x;
    int lane = t & 63, wave = t >> 6;
    int idx = b * SCAN_CHUNK + t * 4;
    int c0 = (idx + 0 < NN) ? cnt[idx + 0] : 0;
    int c1 = (idx + 1 < NN) ? cnt[idx + 1] : 0;
    int c2 = (idx + 2 < NN) ? cnt[idx + 2] : 0;
    int c3 = (idx + 3 < NN) ? cnt[idx + 3] : 0;
    int local = c0 + c1 + c2 + c3;
    int s = local;
    for (int o = 1; o < 64; o <<= 1) {
        int u = __shfl_up(s, o);
        if (lane >= o) s += u;
    }
    if (lane == 63) wsum[wave] = s;
    __syncthreads();
    if (t == 0) {
        int run = 0;
        for (int w = 0; w < 4; w++) { int x = wsum[w]; wsum[w] = run; run += x; }
    }
    __syncthreads();
    int start = boff[b] + wsum[wave] + (s - local);
    if (idx + 0 < NN) { rowptr[idx + 0] = start;                dinv[idx + 0] = rsqrtf((float)(c0 + 1)); }
    if (idx + 1 < NN) { rowptr[idx + 1] = start + c0;           dinv[idx + 1] = rsqrtf((float)(c1 + 1)); }
    if (idx + 2 < NN) { rowptr[idx + 2] = start + c0 + c1;      dinv[idx + 2] = rsqrtf((float)(c2 + 1)); }
    if (idx + 3 < NN) { rowptr[idx + 3] = start + c0 + c1 + c2; dinv[idx + 3] = rsqrtf((float)(c3 + 1)); }
    if (b == 0 && t == 0) rowptr[NN] = NE;
}

// ---------------- scatter2: per-bucket CSR fill ----------------
__global__ __launch_bounds__(256) void scatter2_kernel(const int2* __restrict__ bbuf,
                                                       const int* __restrict__ gtail,
                                                       const int* __restrict__ rowptr,
                                                       int* __restrict__ e_src) {
    __shared__ int fill[800];
    int b = blockIdx.x, t = threadIdx.x;
    int nb = (b * NN + NBUCK - 1) >> 7;
    int ne_ = ((b + 1) * NN + NBUCK - 1) >> 7;
    int range = ne_ - nb;
    for (int i = t; i < range; i += 256) fill[i] = 0;
    __syncthreads();
    int ecnt = gtail[b];
    const int2* p = bbuf + (size_t)b * BCAP;
    for (int i = t; i < ecnt; i += 256) {
        int2 e = p[i];
        int pos = rowptr[e.y] + atomicAdd(&fill[e.y - nb], 1);
        e_src[pos] = e.x;
    }
}

// ---------------- wprep: W1 [256][64] fp32 -> Wtb [64][256] bf16 (transposed) ----------------
__global__ __launch_bounds__(256) void wprep_kernel(const float* __restrict__ W1,
                                                    unsigned short* __restrict__ Wtb) {
    int t = blockIdx.x * 256 + threadIdx.x;    // 16384 threads
    int c = t & 63;
    int k = t >> 6;
    Wtb[c * 256 + k] = f2bf(W1[k * 64 + c]);
}

// ---------------- GEMM1 (MFMA): xw1b = bf16( dinv .* (x @ W1) ) ----------------
// 32 rows/block, 4 waves (2 rowgrp x 2 colgrp), mfma_f32_16x16x32_bf16.
// x staged fp32->bf16 into LDS [32][264] (pad 264: 528B stride = 33*16B, 2-way banks = free);
// Wtb staged into LDS [64][264]. A-frag/B-frag = single ds_read_b128 each.
#define G1_ROWS 32
#define LDP 264
__global__ __launch_bounds__(256) void gemm1_kernel(const float* __restrict__ x,
                                                    const unsigned short* __restrict__ Wtb,
                                                    const float* __restrict__ dinv,
                                                    unsigned short* __restrict__ xw1b) {
    __shared__ unsigned short xt[G1_ROWS * LDP];   // 16896 B
    __shared__ unsigned short wt[HID * LDP];       // 33792 B
    int t = threadIdx.x;
    size_t base = (size_t)blockIdx.x * G1_ROWS;

    // stage x tile: 2048 float4, fully coalesced; cvt to bf16; ds_write 8B
    const float4* xg = (const float4*)(x + base * INC);
#pragma unroll
    for (int ii = 0; ii < 8; ii++) {
        int idx4 = ii * 256 + t;
        float4 v = xg[idx4];
        int f = idx4 * 4;
        int row = f >> 8, k = f & 255;
        ushort4 u;
        u.x = f2bf(v.x); u.y = f2bf(v.y); u.z = f2bf(v.z); u.w = f2bf(v.w);
        *(ushort4*)(xt + row * LDP + k) = u;
    }
    // stage Wt: 2048 int4 coalesced copy
    const int4* wsrc = (const int4*)Wtb;
#pragma unroll
    for (int ii = 0; ii < 8; ii++) {
        int idx4 = ii * 256 + t;
        int4 v = wsrc[idx4];
        int e16 = idx4 * 8;
        int c = e16 >> 8, k = e16 & 255;
        *(int4*)(wt + c * LDP + k) = v;
    }
    __syncthreads();

    int lane = t & 63;
    int wave = t >> 6;
    int l15 = lane & 15;
    int hi = lane >> 4;
    int rgrp = wave & 1;          // row group: 16 rows
    int cgrp = wave >> 1;         // col group: 32 channels
    const unsigned short* ap = xt + (rgrp * 16 + l15) * LDP;
    const unsigned short* bp0 = wt + (cgrp * 32 + l15) * LDP;
    const unsigned short* bp1 = bp0 + 16 * LDP;
    f32x4 acc0 = {0.f, 0.f, 0.f, 0.f};
    f32x4 acc1 = {0.f, 0.f, 0.f, 0.f};
#pragma unroll
    for (int kk = 0; kk < 8; kk++) {
        int ko = kk * 32 + hi * 8;
        short8 a  = *(const short8*)(ap + ko);
        short8 b0 = *(const short8*)(bp0 + ko);
        short8 b1 = *(const short8*)(bp1 + ko);
        acc0 = __builtin_amdgcn_mfma_f32_16x16x32_bf16(a, b0, acc0, 0, 0, 0);
        acc1 = __builtin_amdgcn_mfma_f32_16x16x32_bf16(a, b1, acc1, 0, 0, 0);
    }
    // D: col = lane&15, row = (lane>>4)*4 + i  (m89-verified)
#pragma unroll
    for (int i = 0; i < 4; i++) {
        int grow = (int)base + rgrp * 16 + hi * 4 + i;
        float dv = dinv[grow];
        int c0 = cgrp * 32 + l15;
        xw1b[(size_t)grow * HID + c0]      = f2bf(acc0[i] * dv);
        xw1b[(size_t)grow * HID + c0 + 16] = f2bf(acc1[i] * dv);
    }
}

// ---------------- agg1: h1 = dinv_d*(sum_edges xw1'[s] + xw1'[d]) + b1, fused BN1 stats ----------------
__global__ __launch_bounds__(256) void agg1_kernel(const unsigned short* __restrict__ xw1b,
                                                   const int* __restrict__ rowptr,
                                                   const int* __restrict__ e_src,
                                                   const float* __restrict__ dinv,
                                                   const float* __restrict__ b1,
                                                   float* __restrict__ h1,
                                                   float* __restrict__ sums1) {
    __shared__ float lsum[4][64], lsq[4][64];
    int lane = threadIdx.x & 63;
    int wave = threadIdx.x >> 6;
    int half = lane >> 5;
    int cp = lane & 31;                     // channel pair: channels 2cp, 2cp+1
    int wid = blockIdx.x * 4 + wave;
    int wstride = gridDim.x * 4;
    float bb0 = b1[2 * cp], bb1 = b1[2 * cp + 1];
    float ssum0 = 0.f, ssq0 = 0.f, ssum1 = 0.f, ssq1 = 0.f;
    const ushort2* xw = (const ushort2*)xw1b;   // row = 32 ushort2
    for (int d0 = wid; d0 < NN; d0 += wstride) {
        int d = __builtin_amdgcn_readfirstlane(d0);
        int beg = rowptr[d], end = rowptr[d + 1];
        int EC = end - beg;
        float a0 = 0.f, a1 = 0.f;
        int j = 0;
        for (; j + 7 < EC; j += 8) {           // 8 edges: 4 indep 256B wave-gathers
            int s0 = e_src[beg + j + 0 + half];
            int s1 = e_src[beg + j + 2 + half];
            int s2 = e_src[beg + j + 4 + half];
            int s3 = e_src[beg + j + 6 + half];
            ushort2 u0 = xw[(size_t)s0 * 32 + cp];
            ushort2 u1 = xw[(size_t)s1 * 32 + cp];
            ushort2 u2 = xw[(size_t)s2 * 32 + cp];
            ushort2 u3 = xw[(size_t)s3 * 32 + cp];
            a0 += bf2f(u0.x) + bf2f(u1.x) + bf2f(u2.x) + bf2f(u3.x);
            a1 += bf2f(u0.y) + bf2f(u1.y) + bf2f(u2.y) + bf2f(u3.y);
        }
        for (; j + 1 < EC; j += 2) {           // leftover pairs (<=3)
            int s = e_src[beg + j + half];
            ushort2 u = xw[(size_t)s * 32 + cp];
            a0 += bf2f(u.x);
            a1 += bf2f(u.y);
        }
        // tail: possibly one leftover edge, plus the self-loop row
        bool active = true;
        int s_t;
        if (j < EC) { s_t = half ? d : e_src[beg + j]; }   // half0 = last edge, half1 = self
        else        { s_t = d; active = (half == 0); }     // self only
        if (active) {
            ushort2 u = xw[(size_t)s_t * 32 + cp];
            a0 += bf2f(u.x);
            a1 += bf2f(u.y);
        }
        a0 += __shfl_xor(a0, 32);
        a1 += __shfl_xor(a1, 32);
        float dv = dinv[d];
        float h0 = a0 * dv + bb0;
        float hv1 = a1 * dv + bb1;
        if (half == 0) {
            ((float2*)(h1 + (size_t)d * HID))[cp] = make_float2(h0, hv1);
            ssum0 += h0; ssq0 += h0 * h0;
            ssum1 += hv1; ssq1 += hv1 * hv1;
        }
    }
    if (half == 0) {
        lsum[wave][2 * cp] = ssum0; lsum[wave][2 * cp + 1] = ssum1;
        lsq[wave][2 * cp] = ssq0;   lsq[wave][2 * cp + 1] = ssq1;
    }
    __syncthreads();
    if (wave == 0) {
        float ts = lsum[0][lane] + lsum[1][lane] + lsum[2][lane] + lsum[3][lane];
        float tq = lsq[0][lane] + lsq[1][lane] + lsq[2][lane] + lsq[3][lane];
        atomicAdd(&sums1[lane], ts);
        atomicAdd(&sums1[64 + lane], tq);
    }
}

// ---------------- gemm2: xw2' = dinv .* (relu(BN1(h1)) @ W2) ----------------
__global__ __launch_bounds__(256) void gemm2_kernel(const float* __restrict__ h1,
                                                    const float* __restrict__ sums1,
                                                    const float* __restrict__ g1,
                                                    const float* __restrict__ be1,
                                                    const float* __restrict__ W2,
                                                    const float* __restrict__ dinv,
                                                    float* __restrict__ xw2) {
    int lane = threadIdx.x & 63;
    int row = blockIdx.x * 4 + (threadIdx.x >> 6);
    if (row >= NN) return;
    int c = lane;
    const float invn = 1.0f / (float)NN;
    float mu = sums1[c] * invn;
    float var = sums1[64 + c] * invn - mu * mu;
    float sc = g1[c] * rsqrtf(var + EPSV);
    float sh = be1[c] - mu * sc;
    float h = h1[(size_t)row * HID + c] * sc + sh;
    h = fmaxf(h, 0.f);
    float p0 = h * W2[c * 2 + 0];
    float p1 = h * W2[c * 2 + 1];
    for (int o = 32; o; o >>= 1) {
        p0 += __shfl_xor(p0, o);
        p1 += __shfl_xor(p1, o);
    }
    if (lane == 0) {
        float dv = dinv[row];
        xw2[(size_t)row * 2 + 0] = p0 * dv;
        xw2[(size_t)row * 2 + 1] = p1 * dv;
    }
}

// ---------------- agg2: z2 = dinv_d*(sum xw2'[s] + xw2'[d]) + b2, fused BN2 stats ----------------
__global__ __launch_bounds__(256) void agg2_kernel(const float* __restrict__ xw2,
                                                   const int* __restrict__ rowptr,
                                                   const int* __restrict__ e_src,
                                                   const float* __restrict__ dinv,
                                                   const float* __restrict__ b2,
                                                   float* __restrict__ z2,
                                                   float* __restrict__ sums2) {
    int d = blockIdx.x * 256 + threadIdx.x;
    float z0 = 0.f, z1 = 0.f;
    if (d < NN) {
        int beg = rowptr[d], end = rowptr[d + 1];
        float a0 = 0.f, a1 = 0.f;
        for (int e = beg; e < end; e++) {
            int s = e_src[e];
            a0 += xw2[(size_t)s * 2 + 0];
            a1 += xw2[(size_t)s * 2 + 1];
        }
        a0 += xw2[(size_t)d * 2 + 0];
        a1 += xw2[(size_t)d * 2 + 1];
        float dv = dinv[d];
        z0 = a0 * dv + b2[0];
        z1 = a1 * dv + b2[1];
        z2[(size_t)d * 2 + 0] = z0;
        z2[(size_t)d * 2 + 1] = z1;
    }
    float s0 = z0, s1 = z1, q0 = z0 * z0, q1 = z1 * z1;
    for (int o = 32; o; o >>= 1) {
        s0 += __shfl_xor(s0, o);
        s1 += __shfl_xor(s1, o);
        q0 += __shfl_xor(q0, o);
        q1 += __shfl_xor(q1, o);
    }
    if ((threadIdx.x & 63) == 0) {
        atomicAdd(&sums2[0], s0);
        atomicAdd(&sums2[1], s1);
        atomicAdd(&sums2[2], q0);
        atomicAdd(&sums2[3], q1);
    }
}

// ---------------- decoder: out = BN2(z2) @ Wd + bd ----------------
__global__ __launch_bounds__(256) void decoder_kernel(const float* __restrict__ z2,
                                                      const float* __restrict__ sums2,
                                                      const float* __restrict__ g2,
                                                      const float* __restrict__ be2,
                                                      const float* __restrict__ Wd,
                                                      const float* __restrict__ bd,
                                                      float* __restrict__ out) {
    int g = blockIdx.x * 256 + threadIdx.x;
    int row = g >> 6;
    int c4 = (g & 63) * 4;
    const float invn = 1.0f / (float)NN;
    float mu0 = sums2[0] * invn, mu1 = sums2[1] * invn;
    float v0 = sums2[2] * invn - mu0 * mu0;
    float v1 = sums2[3] * invn - mu1 * mu1;
    float sc0 = g2[0] * rsqrtf(v0 + EPSV), sh0 = be2[0] - mu0 * sc0;
    float sc1 = g2[1] * rsqrtf(v1 + EPSV), sh1 = be2[1] - mu1 * sc1;
    float zb0 = z2[(size_t)row * 2 + 0] * sc0 + sh0;
    float zb1 = z2[(size_t)row * 2 + 1] * sc1 + sh1;
    float4 w0 = *(const float4*)(Wd + c4);
    float4 w1 = *(const float4*)(Wd + INC + c4);
    float4 bb = *(const float4*)(bd + c4);
    float4 o;
    o.x = zb0 * w0.x + zb1 * w1.x + bb.x;
    o.y = zb0 * w0.y + zb1 * w1.y + bb.y;
    o.z = zb0 * w0.z + zb1 * w1.z + bb.z;
    o.w = zb0 * w0.w + zb1 * w1.w + bb.w;
    *(float4*)(out + (size_t)row * INC + c4) = o;
}

// ---------------- launch ----------------
static inline size_t align256(size_t x) { return (x + 255) & ~(size_t)255; }

extern "C" void kernel_launch(void* const* d_in, const int* in_sizes, int n_in,
                              void* d_out, int out_size, void* d_ws, size_t ws_size,
                              hipStream_t stream) {
    const float* x  = (const float*)d_in[0];
    const int*   ei = (const int*)d_in[1];     // [2, E] int32
    const float* W1 = (const float*)d_in[2];
    const float* b1 = (const float*)d_in[3];
    const float* g1 = (const float*)d_in[4];
    const float* be1 = (const float*)d_in[5];
    const float* W2 = (const float*)d_in[6];
    const float* b2 = (const float*)d_in[7];
    const float* g2 = (const float*)d_in[8];
    const float* be2 = (const float*)d_in[9];
    const float* Wd = (const float*)d_in[10];
    const float* bd = (const float*)d_in[11];
    float* out = (float*)d_out;

    const int* src = ei;
    const int* dst = ei + NE;

    char* ws = (char*)d_ws;
    size_t off = 0;
    int* gtail = (int*)(ws + off);      off = align256(off + NBUCK * 4);
    float* sums1 = (float*)(ws + off);  off = align256(off + 128 * 4);
    float* sums2 = (float*)(ws + off);  off = align256(off + 4 * 4);
    size_t zero_bytes = off;
    int* cnt = (int*)(ws + off);        off = align256(off + NN * 4);
    int* rowptr = (int*)(ws + off);     off = align256(off + (NN + 1) * 4);
    float* dinv = (float*)(ws + off);   off = align256(off + NN * 4);
    int* btot = (int*)(ws + off);       off = align256(off + NBLK * 4);
    int* boff = (int*)(ws + off);       off = align256(off + NBLK * 4);
    unsigned short* Wtb = (unsigned short*)(ws + off); off = align256(off + (size_t)HID * INC * 2);
    int2* bbuf = (int2*)(ws + off);     off = align256(off + (size_t)NBUCK * BCAP * 8);
    int* e_src = (int*)(ws + off);      off = align256(off + (size_t)NE * 4 + 64);
    unsigned short* xw1b = (unsigned short*)(ws + off); off = align256(off + (size_t)NN * HID * 2);
    float* h1 = (float*)(ws + off);     off = align256(off + (size_t)NN * HID * 4);
    float* xw2 = (float*)(ws + off);    off = align256(off + (size_t)NN * 2 * 4);
    float* z2 = (float*)(ws + off);     off = align256(off + (size_t)NN * 2 * 4);
    (void)ws_size; (void)in_sizes; (void)n_in; (void)out_size;

    hipMemsetAsync(d_ws, 0, zero_bytes, stream);

    bin_kernel<<<BIN_GRID, 256, 0, stream>>>(src, dst, gtail, bbuf);
    hist2_kernel<<<NBUCK, 256, 0, stream>>>(bbuf, gtail, cnt);
    scan_btot_kernel<<<NBLK, 256, 0, stream>>>(cnt, btot);
    scan_boff_kernel<<<1, 128, 0, stream>>>(btot, boff);
    scan_rowptr_kernel<<<NBLK, 256, 0, stream>>>(cnt, boff, rowptr, dinv);
    scatter2_kernel<<<NBUCK, 256, 0, stream>>>(bbuf, gtail, rowptr, e_src);
    wprep_kernel<<<64, 256, 0, stream>>>(W1, Wtb);
    gemm1_kernel<<<NN / G1_ROWS, 256, 0, stream>>>(x, Wtb, dinv, xw1b);
    agg1_kernel<<<2048, 256, 0, stream>>>(xw1b, rowptr, e_src, dinv, b1, h1, sums1);
    gemm2_kernel<<<(NN + 3) / 4, 256, 0, stream>>>(h1, sums1, g1, be1, W2, dinv, xw2);
    agg2_kernel<<<(NN + 255) / 256, 256, 0, stream>>>(xw2, rowptr, e_src, dinv, b2, z2, sums2);
    decoder_kernel<<<(NN * HID) / 256, 256, 0, stream>>>(z2, sums2, g2, be2, Wd, bd, out);
}

// Round 7
// 402.266 us; speedup vs baseline: 2.3724x; 1.0002x over previous
//
#include <hip/hip_runtime.h>
#include <hip/hip_bf16.h>

#define NN 100000
#define NE 3200000
#define INC 256
#define HID 64
#define OUTC 2
#define EPSV 1e-5f

#define SCAN_CHUNK 1024
#define NBLK ((NN + SCAN_CHUNK - 1) / SCAN_CHUNK)   // 98

#define NBUCK 128
#define BCAP  26000          // mean 25000, sigma ~157 -> +6.4 sigma margin
#define BIN_CHUNK 4096
#define BIN_K 16             // edges per thread (256 threads * 16 = 4096)
#define BIN_GRID ((NE + BIN_CHUNK - 1) / BIN_CHUNK)  // 782

#define NHALF 50000          // dst half size (2 halves x 4 channel-quarters = 8 cohorts)

typedef short short8 __attribute__((ext_vector_type(8)));
typedef float f32x4 __attribute__((ext_vector_type(4)));

static __device__ __forceinline__ float bf2f(unsigned short u) {
    return __uint_as_float((unsigned)u << 16);
}
static __device__ __forceinline__ unsigned short f2bf(float f) {
    __hip_bfloat16 hb = __float2bfloat16(f);   // RNE
    return *(unsigned short*)&hb;
}

// ---------------- bin: partition edges into 128 dst-range buckets ----------------
__global__ __launch_bounds__(256) void bin_kernel(const int* __restrict__ src,
                                                  const int* __restrict__ dst,
                                                  int* __restrict__ gtail,
                                                  int2* __restrict__ bbuf) {
    __shared__ int bcnt[NBUCK], bbase[NBUCK];
    int t = threadIdx.x;
    if (t < NBUCK) bcnt[t] = 0;
    __syncthreads();
    int base = blockIdx.x * BIN_CHUNK;
    int s[BIN_K], d[BIN_K], sl[BIN_K], bk[BIN_K];
#pragma unroll
    for (int r = 0; r < BIN_K; r++) {
        int i = base + r * 256 + t;
        bool v = i < NE;
        s[r] = v ? src[i] : 0;
        d[r] = v ? dst[i] : 0;
        bk[r] = (int)(((unsigned)d[r] * (unsigned)NBUCK) / (unsigned)NN);
        sl[r] = v ? atomicAdd(&bcnt[bk[r]], 1) : 0;
    }
    __syncthreads();
    if (t < NBUCK) bbase[t] = bcnt[t] ? atomicAdd(&gtail[t], bcnt[t]) : 0;
    __syncthreads();
#pragma unroll
    for (int r = 0; r < BIN_K; r++) {
        int i = base + r * 256 + t;
        if (i < NE) {
            int b = bk[r];
            bbuf[(size_t)b * BCAP + bbase[b] + sl[r]] = make_int2(s[r], d[r]);
        }
    }
}

// ---------------- hist2: per-bucket LDS node histogram -> cnt ----------------
__global__ __launch_bounds__(256) void hist2_kernel(const int2* __restrict__ bbuf,
                                                    const int* __restrict__ gtail,
                                                    int* __restrict__ cnt) {
    __shared__ int h[800];
    int b = blockIdx.x, t = threadIdx.x;
    int nb = (b * NN + NBUCK - 1) >> 7;
    int ne_ = ((b + 1) * NN + NBUCK - 1) >> 7;
    int range = ne_ - nb;
    for (int i = t; i < range; i += 256) h[i] = 0;
    __syncthreads();
    int ecnt = gtail[b];
    const int2* p = bbuf + (size_t)b * BCAP;
    for (int i = t; i < ecnt; i += 256) {
        int2 e = p[i];
        atomicAdd(&h[e.y - nb], 1);
    }
    __syncthreads();
    for (int i = t; i < range; i += 256) cnt[nb + i] = h[i];
}

// ---------------- scan step 1: per-chunk totals ----------------
__global__ void scan_btot_kernel(const int* __restrict__ cnt, int* __restrict__ btot) {
    __shared__ int red[4];
    int b = blockIdx.x, t = threadIdx.x;
    int base = b * SCAN_CHUNK;
    int v = 0;
    for (int j = t; j < SCAN_CHUNK; j += 256) {
        int idx = base + j;
        v += (idx < NN) ? cnt[idx] : 0;
    }
    for (int o = 32; o; o >>= 1) v += __shfl_xor(v, o);
    int wave = t >> 6, lane = t & 63;
    if (lane == 0) red[wave] = v;
    __syncthreads();
    if (t == 0) btot[b] = red[0] + red[1] + red[2] + red[3];
}

// ---------------- scan step 2: exclusive scan of chunk totals ----------------
__global__ void scan_boff_kernel(const int* __restrict__ btot, int* __restrict__ boff) {
    __shared__ int wtot[2];
    int t = threadIdx.x;           // 128 threads
    int lane = t & 63, wave = t >> 6;
    int v = (t < NBLK) ? btot[t] : 0;
    int s = v;
    for (int o = 1; o < 64; o <<= 1) {
        int u = __shfl_up(s, o);
        if (lane >= o) s += u;
    }
    if (lane == 63) wtot[wave] = s;
    __syncthreads();
    int add = (wave == 1) ? wtot[0] : 0;
    if (t < NBLK) boff[t] = s - v + add;   // exclusive prefix
}

// ---------------- scan step 3: full rowptr + dinv ----------------
__global__ void scan_rowptr_kernel(const int* __restrict__ cnt, const int* __restrict__ boff,
                                   int* __restrict__ rowptr, float* __restrict__ dinv) {
    __shared__ int wsum[4];
    int b = blockIdx.x, t = threadIdx.x;
    int lane = t & 63, wave = t >> 6;
    int idx = b * SCAN_CHUNK + t * 4;
    int c0 = (idx + 0 < NN) ? cnt[idx + 0] : 0;
    int c1 = (idx + 1 < NN) ? cnt[idx + 1] : 0;
    int c2 = (idx + 2 < NN) ? cnt[idx + 2] : 0;
    int c3 = (idx + 3 < NN) ? cnt[idx + 3] : 0;
    int local = c0 + c1 + c2 + c3;
    int s = local;
    for (int o = 1; o < 64; o <<= 1) {
        int u = __shfl_up(s, o);
        if (lane >= o) s += u;
    }
    if (lane == 63) wsum[wave] = s;
    __syncthreads();
    if (t == 0) {
        int run = 0;
        for (int w = 0; w < 4; w++) { int x = wsum[w]; wsum[w] = run; run += x; }
    }
    __syncthreads();
    int start = boff[b] + wsum[wave] + (s - local);
    if (idx + 0 < NN) { rowptr[idx + 0] = start;                dinv[idx + 0] = rsqrtf((float)(c0 + 1)); }
    if (idx + 1 < NN) { rowptr[idx + 1] = start + c0;           dinv[idx + 1] = rsqrtf((float)(c1 + 1)); }
    if (idx + 2 < NN) { rowptr[idx + 2] = start + c0 + c1;      dinv[idx + 2] = rsqrtf((float)(c2 + 1)); }
    if (idx + 3 < NN) { rowptr[idx + 3] = start + c0 + c1 + c2; dinv[idx + 3] = rsqrtf((float)(c3 + 1)); }
    if (b == 0 && t == 0) rowptr[NN] = NE;
}

// ---------------- scatter2: per-bucket CSR fill ----------------
__global__ __launch_bounds__(256) void scatter2_kernel(const int2* __restrict__ bbuf,
                                                       const int* __restrict__ gtail,
                                                       const int* __restrict__ rowptr,
                                                       int* __restrict__ e_src) {
    __shared__ int fill[800];
    int b = blockIdx.x, t = threadIdx.x;
    int nb = (b * NN + NBUCK - 1) >> 7;
    int ne_ = ((b + 1) * NN + NBUCK - 1) >> 7;
    int range = ne_ - nb;
    for (int i = t; i < range; i += 256) fill[i] = 0;
    __syncthreads();
    int ecnt = gtail[b];
    const int2* p = bbuf + (size_t)b * BCAP;
    for (int i = t; i < ecnt; i += 256) {
        int2 e = p[i];
        int pos = rowptr[e.y] + atomicAdd(&fill[e.y - nb], 1);
        e_src[pos] = e.x;
    }
}

// ---------------- wprep: W1 [256][64] fp32 -> Wtb [64][256] bf16 (transposed) ----------------
__global__ __launch_bounds__(256) void wprep_kernel(const float* __restrict__ W1,
                                                    unsigned short* __restrict__ Wtb) {
    int t = blockIdx.x * 256 + threadIdx.x;    // 16384 threads
    int c = t & 63;
    int k = t >> 6;
    Wtb[c * 256 + k] = f2bf(W1[k * 64 + c]);
}

// ---------------- GEMM1 (MFMA): xw1p[q][N][16] = bf16( dinv .* (x @ W1) ) ----------------
// Output in 4 channel-planes of 3.2 MB each so agg1's gather working set is
// L2-resident per XCD.
#define G1_ROWS 32
#define LDP 264
__global__ __launch_bounds__(256) void gemm1_kernel(const float* __restrict__ x,
                                                    const unsigned short* __restrict__ Wtb,
                                                    const float* __restrict__ dinv,
                                                    unsigned short* __restrict__ xw1p) {
    __shared__ unsigned short xt[G1_ROWS * LDP];   // 16896 B
    __shared__ unsigned short wt[HID * LDP];       // 33792 B
    int t = threadIdx.x;
    size_t base = (size_t)blockIdx.x * G1_ROWS;

    const float4* xg = (const float4*)(x + base * INC);
#pragma unroll
    for (int ii = 0; ii < 8; ii++) {
        int idx4 = ii * 256 + t;
        float4 v = xg[idx4];
        int f = idx4 * 4;
        int row = f >> 8, k = f & 255;
        ushort4 u;
        u.x = f2bf(v.x); u.y = f2bf(v.y); u.z = f2bf(v.z); u.w = f2bf(v.w);
        *(ushort4*)(xt + row * LDP + k) = u;
    }
    const int4* wsrc = (const int4*)Wtb;
#pragma unroll
    for (int ii = 0; ii < 8; ii++) {
        int idx4 = ii * 256 + t;
        int4 v = wsrc[idx4];
        int e16 = idx4 * 8;
        int c = e16 >> 8, k = e16 & 255;
        *(int4*)(wt + c * LDP + k) = v;
    }
    __syncthreads();

    int lane = t & 63;
    int wave = t >> 6;
    int l15 = lane & 15;
    int hi = lane >> 4;
    int rgrp = wave & 1;          // row group: 16 rows
    int cgrp = wave >> 1;         // col group: 32 channels = planes 2*cgrp, 2*cgrp+1
    const unsigned short* ap = xt + (rgrp * 16 + l15) * LDP;
    const unsigned short* bp0 = wt + (cgrp * 32 + l15) * LDP;
    const unsigned short* bp1 = bp0 + 16 * LDP;
    f32x4 acc0 = {0.f, 0.f, 0.f, 0.f};
    f32x4 acc1 = {0.f, 0.f, 0.f, 0.f};
#pragma unroll
    for (int kk = 0; kk < 8; kk++) {
        int ko = kk * 32 + hi * 8;
        short8 a  = *(const short8*)(ap + ko);
        short8 b0 = *(const short8*)(bp0 + ko);
        short8 b1 = *(const short8*)(bp1 + ko);
        acc0 = __builtin_amdgcn_mfma_f32_16x16x32_bf16(a, b0, acc0, 0, 0, 0);
        acc1 = __builtin_amdgcn_mfma_f32_16x16x32_bf16(a, b1, acc1, 0, 0, 0);
    }
    // D: col = lane&15, row = (lane>>4)*4 + i
    unsigned short* p0 = xw1p + (size_t)(cgrp * 2) * NN * 16;
    unsigned short* p1 = p0 + (size_t)NN * 16;
#pragma unroll
    for (int i = 0; i < 4; i++) {
        int grow = (int)base + rgrp * 16 + hi * 4 + i;
        float dv = dinv[grow];
        p0[(size_t)grow * 16 + l15] = f2bf(acc0[i] * dv);
        p1[(size_t)grow * 16 + l15] = f2bf(acc1[i] * dv);
    }
}

// ---------------- agg1: channel-split, XCD-local gathers ----------------
// cohort = blockIdx&7 -> (q = channel quarter, h = dst half). Each cohort
// gathers only plane q (3.2 MB, L2-resident). 8 edges per load instr:
// slot = lane>>3 (edge), lane&7 = ushort2 channel pair. Slot reduce via
// shfl_xor(8/16/32). h1 written as 4 fp32 planes (dense 64B lines).
__global__ __launch_bounds__(256) void agg1_kernel(const unsigned short* __restrict__ xw1p,
                                                   const int* __restrict__ rowptr,
                                                   const int* __restrict__ e_src,
                                                   const float* __restrict__ dinv,
                                                   const float* __restrict__ b1,
                                                   float* __restrict__ h1p,
                                                   float* __restrict__ sums1) {
    __shared__ float lsum[4][16], lsq[4][16];
    int t = threadIdx.x;
    int lane = t & 63;
    int wave = t >> 6;
    int slot = lane >> 3;          // 0..7: edge within group
    int cl = lane & 7;             // channel pair within 16-ch plane
    int cohort = blockIdx.x & 7;
    int q = cohort & 3;            // channel quarter
    int h = cohort >> 2;           // dst half
    const ushort2* plane = (const ushort2*)(xw1p + (size_t)q * NN * 16);
    float* hp = h1p + (size_t)q * NN * 16;
    float bb0 = b1[q * 16 + cl * 2 + 0];
    float bb1 = b1[q * 16 + cl * 2 + 1];
    int wid = (blockIdx.x >> 3) * 4 + wave;       // 0..1023 within cohort
    int dlo = h * NHALF;
    float ssum0 = 0.f, ssq0 = 0.f, ssum1 = 0.f, ssq1 = 0.f;
    for (int d0 = dlo + wid; d0 < dlo + NHALF; d0 += 1024) {
        int d = __builtin_amdgcn_readfirstlane(d0);
        int beg = rowptr[d], end = rowptr[d + 1];
        int EC = end - beg;
        int G = EC >> 3, rem = EC & 7;
        float a0 = 0.f, a1 = 0.f;
        int g = 0;
        for (; g + 1 < G; g += 2) {               // 16 edges, 2 gathers in flight
            int sa = e_src[beg + g * 8 + slot];
            int sb = e_src[beg + g * 8 + 8 + slot];
            ushort2 ua = plane[(size_t)sa * 8 + cl];
            ushort2 ub = plane[(size_t)sb * 8 + cl];
            a0 += bf2f(ua.x) + bf2f(ub.x);
            a1 += bf2f(ua.y) + bf2f(ub.y);
        }
        if (g < G) {
            int sa = e_src[beg + g * 8 + slot];
            ushort2 ua = plane[(size_t)sa * 8 + cl];
            a0 += bf2f(ua.x);
            a1 += bf2f(ua.y);
        }
        // tail: rem leftover edges + self-loop (rem+1 <= 8 items)
        if (slot <= rem) {
            int s_t = (slot < rem) ? e_src[beg + G * 8 + slot] : d;
            ushort2 u = plane[(size_t)s_t * 8 + cl];
            a0 += bf2f(u.x);
            a1 += bf2f(u.y);
        }
        a0 += __shfl_xor(a0, 8);  a1 += __shfl_xor(a1, 8);
        a0 += __shfl_xor(a0, 16); a1 += __shfl_xor(a1, 16);
        a0 += __shfl_xor(a0, 32); a1 += __shfl_xor(a1, 32);
        float dv = dinv[d];
        float h0 = a0 * dv + bb0;
        float hv1 = a1 * dv + bb1;
        if (slot == 0) {
            *(float2*)(hp + (size_t)d * 16 + cl * 2) = make_float2(h0, hv1);
            ssum0 += h0; ssq0 += h0 * h0;
            ssum1 += hv1; ssq1 += hv1 * hv1;
        }
    }
    if (slot == 0) {
        lsum[wave][cl * 2] = ssum0; lsum[wave][cl * 2 + 1] = ssum1;
        lsq[wave][cl * 2] = ssq0;   lsq[wave][cl * 2 + 1] = ssq1;
    }
    __syncthreads();
    if (t < 16) {
        float ts = lsum[0][t] + lsum[1][t] + lsum[2][t] + lsum[3][t];
        float tq = lsq[0][t] + lsq[1][t] + lsq[2][t] + lsq[3][t];
        atomicAdd(&sums1[q * 16 + t], ts);
        atomicAdd(&sums1[64 + q * 16 + t], tq);
    }
}

// ---------------- gemm2: xw2' = dinv .* (relu(BN1(h1)) @ W2) ----------------
__global__ __launch_bounds__(256) void gemm2_kernel(const float* __restrict__ h1p,
                                                    const float* __restrict__ sums1,
                                                    const float* __restrict__ g1,
                                                    const float* __restrict__ be1,
                                                    const float* __restrict__ W2,
                                                    const float* __restrict__ dinv,
                                                    float* __restrict__ xw2) {
    int lane = threadIdx.x & 63;
    int row = blockIdx.x * 4 + (threadIdx.x >> 6);
    if (row >= NN) return;
    int c = lane;
    const float invn = 1.0f / (float)NN;
    float mu = sums1[c] * invn;
    float var = sums1[64 + c] * invn - mu * mu;
    float sc = g1[c] * rsqrtf(var + EPSV);
    float sh = be1[c] - mu * sc;
    float hv = h1p[(size_t)(c >> 4) * NN * 16 + (size_t)row * 16 + (c & 15)] * sc + sh;
    hv = fmaxf(hv, 0.f);
    float p0 = hv * W2[c * 2 + 0];
    float p1 = hv * W2[c * 2 + 1];
    for (int o = 32; o; o >>= 1) {
        p0 += __shfl_xor(p0, o);
        p1 += __shfl_xor(p1, o);
    }
    if (lane == 0) {
        float dv = dinv[row];
        xw2[(size_t)row * 2 + 0] = p0 * dv;
        xw2[(size_t)row * 2 + 1] = p1 * dv;
    }
}

// ---------------- agg2: z2 = dinv_d*(sum xw2'[s] + xw2'[d]) + b2, fused BN2 stats ----------------
__global__ __launch_bounds__(256) void agg2_kernel(const float* __restrict__ xw2,
                                                   const int* __restrict__ rowptr,
                                                   const int* __restrict__ e_src,
                                                   const float* __restrict__ dinv,
                                                   const float* __restrict__ b2,
                                                   float* __restrict__ z2,
                                                   float* __restrict__ sums2) {
    int d = blockIdx.x * 256 + threadIdx.x;
    float z0 = 0.f, z1 = 0.f;
    if (d < NN) {
        int beg = rowptr[d], end = rowptr[d + 1];
        float a0 = 0.f, a1 = 0.f;
        for (int e = beg; e < end; e++) {
            int s = e_src[e];
            a0 += xw2[(size_t)s * 2 + 0];
            a1 += xw2[(size_t)s * 2 + 1];
        }
        a0 += xw2[(size_t)d * 2 + 0];
        a1 += xw2[(size_t)d * 2 + 1];
        float dv = dinv[d];
        z0 = a0 * dv + b2[0];
        z1 = a1 * dv + b2[1];
        z2[(size_t)d * 2 + 0] = z0;
        z2[(size_t)d * 2 + 1] = z1;
    }
    float s0 = z0, s1 = z1, q0 = z0 * z0, q1 = z1 * z1;
    for (int o = 32; o; o >>= 1) {
        s0 += __shfl_xor(s0, o);
        s1 += __shfl_xor(s1, o);
        q0 += __shfl_xor(q0, o);
        q1 += __shfl_xor(q1, o);
    }
    if ((threadIdx.x & 63) == 0) {
        atomicAdd(&sums2[0], s0);
        atomicAdd(&sums2[1], s1);
        atomicAdd(&sums2[2], q0);
        atomicAdd(&sums2[3], q1);
    }
}

// ---------------- decoder: out = BN2(z2) @ Wd + bd ----------------
__global__ __launch_bounds__(256) void decoder_kernel(const float* __restrict__ z2,
                                                      const float* __restrict__ sums2,
                                                      const float* __restrict__ g2,
                                                      const float* __restrict__ be2,
                                                      const float* __restrict__ Wd,
                                                      const float* __restrict__ bd,
                                                      float* __restrict__ out) {
    int g = blockIdx.x * 256 + threadIdx.x;
    int row = g >> 6;
    int c4 = (g & 63) * 4;
    const float invn = 1.0f / (float)NN;
    float mu0 = sums2[0] * invn, mu1 = sums2[1] * invn;
    float v0 = sums2[2] * invn - mu0 * mu0;
    float v1 = sums2[3] * invn - mu1 * mu1;
    float sc0 = g2[0] * rsqrtf(v0 + EPSV), sh0 = be2[0] - mu0 * sc0;
    float sc1 = g2[1] * rsqrtf(v1 + EPSV), sh1 = be2[1] - mu1 * sc1;
    float zb0 = z2[(size_t)row * 2 + 0] * sc0 + sh0;
    float zb1 = z2[(size_t)row * 2 + 1] * sc1 + sh1;
    float4 w0 = *(const float4*)(Wd + c4);
    float4 w1 = *(const float4*)(Wd + INC + c4);
    float4 bb = *(const float4*)(bd + c4);
    float4 o;
    o.x = zb0 * w0.x + zb1 * w1.x + bb.x;
    o.y = zb0 * w0.y + zb1 * w1.y + bb.y;
    o.z = zb0 * w0.z + zb1 * w1.z + bb.z;
    o.w = zb0 * w0.w + zb1 * w1.w + bb.w;
    *(float4*)(out + (size_t)row * INC + c4) = o;
}

// ---------------- launch ----------------
static inline size_t align256(size_t x) { return (x + 255) & ~(size_t)255; }

extern "C" void kernel_launch(void* const* d_in, const int* in_sizes, int n_in,
                              void* d_out, int out_size, void* d_ws, size_t ws_size,
                              hipStream_t stream) {
    const float* x  = (const float*)d_in[0];
    const int*   ei = (const int*)d_in[1];     // [2, E] int32
    const float* W1 = (const float*)d_in[2];
    const float* b1 = (const float*)d_in[3];
    const float* g1 = (const float*)d_in[4];
    const float* be1 = (const float*)d_in[5];
    const float* W2 = (const float*)d_in[6];
    const float* b2 = (const float*)d_in[7];
    const float* g2 = (const float*)d_in[8];
    const float* be2 = (const float*)d_in[9];
    const float* Wd = (const float*)d_in[10];
    const float* bd = (const float*)d_in[11];
    float* out = (float*)d_out;

    const int* src = ei;
    const int* dst = ei + NE;

    char* ws = (char*)d_ws;
    size_t off = 0;
    int* gtail = (int*)(ws + off);      off = align256(off + NBUCK * 4);
    float* sums1 = (float*)(ws + off);  off = align256(off + 128 * 4);
    float* sums2 = (float*)(ws + off);  off = align256(off + 4 * 4);
    size_t zero_bytes = off;
    int* cnt = (int*)(ws + off);        off = align256(off + NN * 4);
    int* rowptr = (int*)(ws + off);     off = align256(off + (NN + 1) * 4);
    float* dinv = (float*)(ws + off);   off = align256(off + NN * 4);
    int* btot = (int*)(ws + off);       off = align256(off + NBLK * 4);
    int* boff = (int*)(ws + off);       off = align256(off + NBLK * 4);
    unsigned short* Wtb = (unsigned short*)(ws + off); off = align256(off + (size_t)HID * INC * 2);
    int2* bbuf = (int2*)(ws + off);     off = align256(off + (size_t)NBUCK * BCAP * 8);
    int* e_src = (int*)(ws + off);      off = align256(off + (size_t)NE * 4 + 64);
    unsigned short* xw1p = (unsigned short*)(ws + off); off = align256(off + (size_t)NN * HID * 2);
    float* h1p = (float*)(ws + off);    off = align256(off + (size_t)NN * HID * 4);
    float* xw2 = (float*)(ws + off);    off = align256(off + (size_t)NN * 2 * 4);
    float* z2 = (float*)(ws + off);     off = align256(off + (size_t)NN * 2 * 4);
    (void)ws_size; (void)in_sizes; (void)n_in; (void)out_size;

    hipMemsetAsync(d_ws, 0, zero_bytes, stream);

    bin_kernel<<<BIN_GRID, 256, 0, stream>>>(src, dst, gtail, bbuf);
    hist2_kernel<<<NBUCK, 256, 0, stream>>>(bbuf, gtail, cnt);
    scan_btot_kernel<<<NBLK, 256, 0, stream>>>(cnt, btot);
    scan_boff_kernel<<<1, 128, 0, stream>>>(btot, boff);
    scan_rowptr_kernel<<<NBLK, 256, 0, stream>>>(cnt, boff, rowptr, dinv);
    scatter2_kernel<<<NBUCK, 256, 0, stream>>>(bbuf, gtail, rowptr, e_src);
    wprep_kernel<<<64, 256, 0, stream>>>(W1, Wtb);
    gemm1_kernel<<<NN / G1_ROWS, 256, 0, stream>>>(x, Wtb, dinv, xw1p);
    agg1_kernel<<<2048, 256, 0, stream>>>(xw1p, rowptr, e_src, dinv, b1, h1p, sums1);
    gemm2_kernel<<<(NN + 3) / 4, 256, 0, stream>>>(h1p, sums1, g1, be1, W2, dinv, xw2);
    agg2_kernel<<<(NN + 255) / 256, 256, 0, stream>>>(xw2, rowptr, e_src, dinv, b2, z2, sums2);
    decoder_kernel<<<(NN * HID) / 256, 256, 0, stream>>>(z2, sums2, g2, be2, Wd, bd, out);
}